// Round 1
// baseline (306.994 us; speedup 1.0000x reference)
//
#include <hip/hip_runtime.h>
#include <hip/hip_bf16.h>
#include <stdint.h>

// CausalSelfAttention: x[2,2048,1024] -> qkv -> 16-head causal attn -> proj.
// bf16 MFMA pipeline, fp32 accumulation everywhere.

typedef __attribute__((ext_vector_type(4))) float  f32x4;
typedef __attribute__((ext_vector_type(8))) __bf16 bf16x8;
typedef __attribute__((ext_vector_type(4))) short  s16x4;
typedef __attribute__((ext_vector_type(8))) short  s16x8;

#define MFMA(a, b, c) __builtin_amdgcn_mfma_f32_16x16x32_bf16((a), (b), (c), 0, 0, 0)

__device__ __forceinline__ short f2bf(float x) {  // round-to-nearest-even f32->bf16
  union { float f; unsigned u; } v; v.f = x;
  unsigned r = v.u + 0x7FFFu + ((v.u >> 16) & 1u);
  return (short)(r >> 16);
}

__device__ __forceinline__ void gload16(const void* gptr, void* lptr) {
  __builtin_amdgcn_global_load_lds(
      (const __attribute__((address_space(1))) void*)gptr,
      (__attribute__((address_space(3))) void*)lptr, 16, 0, 0);
}

// ---------------- conversion kernels ----------------

__global__ __launch_bounds__(256) void k_f32_to_bf16(const float* __restrict__ in,
                                                     short* __restrict__ out, int n) {
  int i = (blockIdx.x * 256 + threadIdx.x) * 4;
  if (i >= n) return;
  float4 v = *(const float4*)(in + i);
  s16x4 o;
  o[0] = f2bf(v.x); o[1] = f2bf(v.y); o[2] = f2bf(v.z); o[3] = f2bf(v.w);
  *(s16x4*)(out + i) = o;
}

// W [R][C] fp32 row-major  ->  Wt [C][R] bf16 (i.e. [n][k] layout for GEMM B^T)
__global__ __launch_bounds__(256) void k_transpose_bf(const float* __restrict__ W,
                                                      short* __restrict__ Wt, int R, int C) {
  __shared__ float tile[32][33];
  const int tx = threadIdx.x & 31, ty = threadIdx.x >> 5;  // ty 0..7
  const int bx = blockIdx.x * 32, by = blockIdx.y * 32;
#pragma unroll
  for (int i = 0; i < 4; ++i)
    tile[ty + i * 8][tx] = W[(long)(by + ty + i * 8) * C + bx + tx];
  __syncthreads();
#pragma unroll
  for (int i = 0; i < 4; ++i)
    Wt[(long)(bx + ty + i * 8) * R + by + tx] = f2bf(tile[tx][ty + i * 8]);
}

// ---------------- GEMM: C[M][N] = A[M][K] * Bt[N][K]^T + bias ----------------
// 128x128 tile, BK=32, 4 waves (2x2 of 64x64), m97 2-barrier structure.
// EPI==0: scatter to Q[b,h,s,d], K[b,h,s,d], Vt[b,h,d,s] (bf16)
// EPI==1: fp32 row-major output

template <int EPI>
__global__ __launch_bounds__(256) void k_gemm(const short* __restrict__ A,
                                              const short* __restrict__ Bt,
                                              const float* __restrict__ bias,
                                              int M, int N, int K,
                                              short* __restrict__ q_out,
                                              short* __restrict__ k_out,
                                              short* __restrict__ vt_out,
                                              float* __restrict__ c_out) {
  __shared__ short As[128 * 32];
  __shared__ short Bs[128 * 32];
  const int tid  = threadIdx.x;
  const int lane = tid & 63;
  const int wave = tid >> 6;
  const int wm = (wave >> 1) * 64, wn = (wave & 1) * 64;
  const int bm = blockIdx.y * 128, bn = blockIdx.x * 128;
  const int sr = tid >> 2, sc = (tid & 3) * 8;
  const short* Ag = A + (long)(bm + sr) * K + sc;
  const short* Bg = Bt + (long)(bn + sr) * K + sc;
  short* Asl = As + tid * 8;
  short* Bsl = Bs + tid * 8;
  const int fr = lane & 15, fg = lane >> 4;

  f32x4 acc[4][4];
#pragma unroll
  for (int i = 0; i < 4; ++i)
#pragma unroll
    for (int j = 0; j < 4; ++j) acc[i][j] = (f32x4){0.f, 0.f, 0.f, 0.f};

  for (int kt = 0; kt < K; kt += 32) {
    gload16(Ag + kt, Asl);
    gload16(Ag + kt + 64 * K, Asl + 2048);
    gload16(Bg + kt, Bsl);
    gload16(Bg + kt + 64 * K, Bsl + 2048);
    __syncthreads();  // drains vmcnt: staged data visible
    bf16x8 af[4], bfr[4];
    const short* Ar = As + (wm + fr) * 32 + fg * 8;
    const short* Br = Bs + (wn + fr) * 32 + fg * 8;
#pragma unroll
    for (int mi = 0; mi < 4; ++mi) af[mi] = *(const bf16x8*)(Ar + mi * 16 * 32);
#pragma unroll
    for (int ni = 0; ni < 4; ++ni) bfr[ni] = *(const bf16x8*)(Br + ni * 16 * 32);
#pragma unroll
    for (int mi = 0; mi < 4; ++mi)
#pragma unroll
      for (int ni = 0; ni < 4; ++ni)
        acc[mi][ni] = MFMA(af[mi], bfr[ni], acc[mi][ni]);
    __syncthreads();  // compute done before next-tile overwrite
  }

#pragma unroll
  for (int mi = 0; mi < 4; ++mi) {
#pragma unroll
    for (int ni = 0; ni < 4; ++ni) {
      const int gcol  = bn + wn + ni * 16 + fr;
      const float bv  = bias[gcol];
      const int grow0 = bm + wm + mi * 16 + fg * 4;
      if (EPI == 0) {
        const int which = gcol >> 10;       // uniform per block (BN=128 within 1024)
        const int e = gcol & 1023;
        const int h = e >> 6, d = e & 63;
#pragma unroll
        for (int r = 0; r < 4; ++r) {
          const int mrow = grow0 + r;
          const int b = mrow >> 11, s = mrow & 2047;
          const short val = f2bf(acc[mi][ni][r] + bv);
          if (which == 0)      q_out[((long)(b * 16 + h) * 2048 + s) * 64 + d] = val;
          else if (which == 1) k_out[((long)(b * 16 + h) * 2048 + s) * 64 + d] = val;
          else                 vt_out[((long)(b * 16 + h) * 64 + d) * 2048 + s] = val;
        }
      } else {
#pragma unroll
        for (int r = 0; r < 4; ++r)
          c_out[(long)(grow0 + r) * N + gcol] = acc[mi][ni][r] + bv;
      }
    }
  }
}

// ---------------- causal flash attention ----------------
// grid (S/64, B*H), 256 threads = 4 independent waves, 16 q-rows each, KV tile 32.
// Swapped QK^T: lane owns score row q=lane&15; k spread over lane>>4 groups.
// PV as O^T = V^T * P^T so rescale/divide are lane-local.

__global__ __launch_bounds__(256) void k_attn(const short* __restrict__ Qb,
                                              const short* __restrict__ Kb,
                                              const short* __restrict__ Vt,
                                              short* __restrict__ Y) {
  __shared__ short plds[4][16][40];   // per-wave P tile, padded stride (bank-friendly)
  __shared__ float ot[4][16][65];     // per-wave output transpose buffer
  const int qt = blockIdx.x, bh = blockIdx.y;
  const int b = bh >> 4, h = bh & 15;
  const int wave = threadIdx.x >> 6, lane = threadIdx.x & 63;
  const int qw = qt * 64 + wave * 16;
  const int ql = lane & 15, g = lane >> 4;
  const short* Qp = Qb + ((long)bh * 2048 + qw) * 64;
  const short* Kp = Kb + (long)bh * 2048 * 64;
  const short* Vp = Vt + (long)bh * 64 * 2048;

  const bf16x8 qf0 = *(const bf16x8*)(Qp + ql * 64 + g * 8);
  const bf16x8 qf1 = *(const bf16x8*)(Qp + ql * 64 + 32 + g * 8);

  f32x4 o[4];
#pragma unroll
  for (int df = 0; df < 4; ++df) o[df] = (f32x4){0.f, 0.f, 0.f, 0.f};
  float m = -1e30f, l = 0.f;
  const int qa = qw + ql;
  const int nkv = (qw + 16 + 31) >> 5;

  for (int t = 0; t < nkv; ++t) {
    const int k0 = t * 32;
    float s[8];
#pragma unroll
    for (int kf = 0; kf < 2; ++kf) {
      const short* Kr = Kp + (long)(k0 + kf * 16 + ql) * 64 + g * 8;
      const bf16x8 ka = *(const bf16x8*)Kr;
      const bf16x8 kb = *(const bf16x8*)(Kr + 32);
      f32x4 z = (f32x4){0.f, 0.f, 0.f, 0.f};
      z = MFMA(ka, qf0, z);             // ST[k][q] over d=0..31
      z = MFMA(kb, qf1, z);             // += over d=32..63
#pragma unroll
      for (int r = 0; r < 4; ++r) {
        const int kabs = k0 + kf * 16 + g * 4 + r;
        s[kf * 4 + r] = (kabs <= qa) ? z[r] * 0.125f : -1e30f;
      }
    }
    float tmax = s[0];
#pragma unroll
    for (int j = 1; j < 8; ++j) tmax = fmaxf(tmax, s[j]);
    tmax = fmaxf(tmax, __shfl_xor(tmax, 16));
    tmax = fmaxf(tmax, __shfl_xor(tmax, 32));
    const float nm  = fmaxf(m, tmax);
    const float fac = __expf(m - nm);
    float p[8];
    float ts = 0.f;
#pragma unroll
    for (int j = 0; j < 8; ++j) { p[j] = __expf(s[j] - nm); ts += p[j]; }
    ts += __shfl_xor(ts, 16);
    ts += __shfl_xor(ts, 32);
    l = l * fac + ts;
    m = nm;
#pragma unroll
    for (int df = 0; df < 4; ++df) o[df] *= fac;

    // P -> LDS (A-fragment layout round trip), k index = kf*16 + g*4 + r
#pragma unroll
    for (int kf = 0; kf < 2; ++kf) {
      s16x4 pk;
      pk[0] = f2bf(p[kf * 4 + 0]);
      pk[1] = f2bf(p[kf * 4 + 1]);
      pk[2] = f2bf(p[kf * 4 + 2]);
      pk[3] = f2bf(p[kf * 4 + 3]);
      *(s16x4*)&plds[wave][ql][kf * 16 + g * 4] = pk;
    }
    const bf16x8 pf = *(const bf16x8*)&plds[wave][ql][g * 8];

    const int kk = k0 + g * 8;
#pragma unroll
    for (int df = 0; df < 4; ++df) {
      const short* Vr = Vp + (long)(df * 16 + ql) * 2048 + kk;
      const bf16x8 vf = *(const bf16x8*)Vr;
      o[df] = MFMA(vf, pf, o[df]);      // O^T[d][q]
    }
  }

  const float linv = 1.f / l;
#pragma unroll
  for (int df = 0; df < 4; ++df)
#pragma unroll
    for (int r = 0; r < 4; ++r)
      ot[wave][ql][df * 16 + g * 4 + r] = o[df][r] * linv;

  // transpose within wave, coalesced bf16 store: lane -> (row lane>>2, 16-col chunk lane&3)
  const int q2 = lane >> 2, c4 = (lane & 3) * 16;
  short* Yp = Y + ((long)(b * 2048 + qw + q2)) * 1024 + h * 64 + c4;
  s16x8 y0, y1;
#pragma unroll
  for (int j = 0; j < 8; ++j) {
    y0[j] = f2bf(ot[wave][q2][c4 + j]);
    y1[j] = f2bf(ot[wave][q2][c4 + 8 + j]);
  }
  *(s16x8*)Yp = y0;
  *((s16x8*)(Yp + 8)) = y1;
}

// ---------------- launch ----------------

extern "C" void kernel_launch(void* const* d_in, const int* in_sizes, int n_in,
                              void* d_out, int out_size, void* d_ws, size_t ws_size,
                              hipStream_t stream) {
  const float* x      = (const float*)d_in[0];
  const float* W_attn = (const float*)d_in[1];
  const float* b_attn = (const float*)d_in[2];
  const float* W_proj = (const float*)d_in[3];
  const float* b_proj = (const float*)d_in[4];
  float* out = (float*)d_out;

  char* ws = (char*)d_ws;
  short* x_bf = (short*)(ws);                    //  8 MB  [4096][1024]
  short* Wt_a = (short*)(ws + 8388608);          //  6 MB  [3072][1024]
  short* Wt_p = (short*)(ws + 14680064);         //  2 MB  [1024][1024]
  short* Qb   = (short*)(ws + 16777216);         //  8 MB  [2,16,2048,64]
  short* Kb   = (short*)(ws + 25165824);         //  8 MB  [2,16,2048,64]
  short* Vtb  = (short*)(ws + 33554432);         //  8 MB  [2,16,64,2048]
  short* y_bf = (short*)(ws + 41943040);         //  8 MB  [4096][1024]

  k_f32_to_bf16<<<4096, 256, 0, stream>>>(x, x_bf, 4194304);
  k_transpose_bf<<<dim3(96, 32), 256, 0, stream>>>(W_attn, Wt_a, 1024, 3072);
  k_transpose_bf<<<dim3(32, 32), 256, 0, stream>>>(W_proj, Wt_p, 1024, 1024);
  k_gemm<0><<<dim3(24, 32), 256, 0, stream>>>(x_bf, Wt_a, b_attn, 4096, 3072, 1024,
                                              Qb, Kb, Vtb, nullptr);
  k_attn<<<dim3(32, 32), 256, 0, stream>>>(Qb, Kb, Vtb, y_bf);
  k_gemm<1><<<dim3(8, 32), 256, 0, stream>>>(y_bf, Wt_p, b_proj, 4096, 1024, 1024,
                                             nullptr, nullptr, nullptr, out);
}

// Round 2
// 297.436 us; speedup vs baseline: 1.0321x; 1.0321x over previous
//
#include <hip/hip_runtime.h>
#include <hip/hip_bf16.h>
#include <stdint.h>

// CausalSelfAttention: x[2,2048,1024] -> qkv -> 16-head causal attn -> proj.
// bf16 MFMA pipeline, fp32 accumulation everywhere.

typedef __attribute__((ext_vector_type(4))) float  f32x4;
typedef __attribute__((ext_vector_type(8))) __bf16 bf16x8;
typedef __attribute__((ext_vector_type(4))) short  s16x4;
typedef __attribute__((ext_vector_type(8))) short  s16x8;

#define MFMA(a, b, c) __builtin_amdgcn_mfma_f32_16x16x32_bf16((a), (b), (c), 0, 0, 0)

#if __has_builtin(__builtin_amdgcn_mfma_f32_16x16x16bf16_1k)
#define HAVE_MFMA16 1
#define MFMA16(a, b, c) __builtin_amdgcn_mfma_f32_16x16x16bf16_1k((a), (b), (c), 0, 0, 0)
#else
#define HAVE_MFMA16 0
#endif

__device__ __forceinline__ short f2bf(float x) {  // round-to-nearest-even f32->bf16
  union { float f; unsigned u; } v; v.f = x;
  unsigned r = v.u + 0x7FFFu + ((v.u >> 16) & 1u);
  return (short)(r >> 16);
}

__device__ __forceinline__ void gload16(const void* gptr, void* lptr) {
  __builtin_amdgcn_global_load_lds(
      (const __attribute__((address_space(1))) void*)gptr,
      (__attribute__((address_space(3))) void*)lptr, 16, 0, 0);
}

// ---------------- conversion kernels ----------------

__global__ __launch_bounds__(256) void k_f32_to_bf16(const float* __restrict__ in,
                                                     short* __restrict__ out, int n) {
  int i = (blockIdx.x * 256 + threadIdx.x) * 4;
  if (i >= n) return;
  float4 v = *(const float4*)(in + i);
  s16x4 o;
  o[0] = f2bf(v.x); o[1] = f2bf(v.y); o[2] = f2bf(v.z); o[3] = f2bf(v.w);
  *(s16x4*)(out + i) = o;
}

// W [R][C] fp32 row-major  ->  Wt [C][R] bf16 (i.e. [n][k] layout for GEMM B^T)
__global__ __launch_bounds__(256) void k_transpose_bf(const float* __restrict__ W,
                                                      short* __restrict__ Wt, int R, int C) {
  __shared__ float tile[32][33];
  const int tx = threadIdx.x & 31, ty = threadIdx.x >> 5;  // ty 0..7
  const int bx = blockIdx.x * 32, by = blockIdx.y * 32;
#pragma unroll
  for (int i = 0; i < 4; ++i)
    tile[ty + i * 8][tx] = W[(long)(by + ty + i * 8) * C + bx + tx];
  __syncthreads();
#pragma unroll
  for (int i = 0; i < 4; ++i)
    Wt[(long)(bx + ty + i * 8) * R + by + tx] = f2bf(tile[tx][ty + i * 8]);
}

// ---------------- GEMM: C[M][N] = A[M][K] * Bt[N][K]^T + bias ----------------
// 128x128 tile, BK=32, 4 waves (2x2 of 64x64), m97 2-barrier structure.
// EPI==0: scatter to Q[b,h,s,d], K[b,h,s,d], Vt[b,h,d,s] (bf16)
// EPI==1: fp32 row-major output

template <int EPI>
__global__ __launch_bounds__(256) void k_gemm(const short* __restrict__ A,
                                              const short* __restrict__ Bt,
                                              const float* __restrict__ bias,
                                              int M, int N, int K,
                                              short* __restrict__ q_out,
                                              short* __restrict__ k_out,
                                              short* __restrict__ vt_out,
                                              float* __restrict__ c_out) {
  __shared__ short As[128 * 32];
  __shared__ short Bs[128 * 32];
  const int tid  = threadIdx.x;
  const int lane = tid & 63;
  const int wave = tid >> 6;
  const int wm = (wave >> 1) * 64, wn = (wave & 1) * 64;
  const int bm = blockIdx.y * 128, bn = blockIdx.x * 128;
  const int sr = tid >> 2, sc = (tid & 3) * 8;
  const short* Ag = A + (long)(bm + sr) * K + sc;
  const short* Bg = Bt + (long)(bn + sr) * K + sc;
  short* Asl = As + tid * 8;
  short* Bsl = Bs + tid * 8;
  const int fr = lane & 15, fg = lane >> 4;

  f32x4 acc[4][4];
#pragma unroll
  for (int i = 0; i < 4; ++i)
#pragma unroll
    for (int j = 0; j < 4; ++j) acc[i][j] = (f32x4){0.f, 0.f, 0.f, 0.f};

  for (int kt = 0; kt < K; kt += 32) {
    gload16(Ag + kt, Asl);
    gload16(Ag + kt + 64 * K, Asl + 2048);
    gload16(Bg + kt, Bsl);
    gload16(Bg + kt + 64 * K, Bsl + 2048);
    __syncthreads();  // drains vmcnt: staged data visible
    bf16x8 af[4], bfr[4];
    const short* Ar = As + (wm + fr) * 32 + fg * 8;
    const short* Br = Bs + (wn + fr) * 32 + fg * 8;
#pragma unroll
    for (int mi = 0; mi < 4; ++mi) af[mi] = *(const bf16x8*)(Ar + mi * 16 * 32);
#pragma unroll
    for (int ni = 0; ni < 4; ++ni) bfr[ni] = *(const bf16x8*)(Br + ni * 16 * 32);
#pragma unroll
    for (int mi = 0; mi < 4; ++mi)
#pragma unroll
      for (int ni = 0; ni < 4; ++ni)
        acc[mi][ni] = MFMA(af[mi], bfr[ni], acc[mi][ni]);
    __syncthreads();  // compute done before next-tile overwrite
  }

#pragma unroll
  for (int mi = 0; mi < 4; ++mi) {
#pragma unroll
    for (int ni = 0; ni < 4; ++ni) {
      const int gcol  = bn + wn + ni * 16 + fr;
      const float bv  = bias[gcol];
      const int grow0 = bm + wm + mi * 16 + fg * 4;
      if (EPI == 0) {
        const int which = gcol >> 10;       // uniform per block (BN=128 within 1024)
        const int e = gcol & 1023;
        const int h = e >> 6, d = e & 63;
#pragma unroll
        for (int r = 0; r < 4; ++r) {
          const int mrow = grow0 + r;
          const int b = mrow >> 11, s = mrow & 2047;
          const short val = f2bf(acc[mi][ni][r] + bv);
          if (which == 0)      q_out[((long)(b * 16 + h) * 2048 + s) * 64 + d] = val;
          else if (which == 1) k_out[((long)(b * 16 + h) * 2048 + s) * 64 + d] = val;
          else                 vt_out[((long)(b * 16 + h) * 64 + d) * 2048 + s] = val;
        }
      } else {
#pragma unroll
        for (int r = 0; r < 4; ++r)
          c_out[(long)(grow0 + r) * N + gcol] = acc[mi][ni][r] + bv;
      }
    }
  }
}

// ---------------- causal flash attention ----------------
// grid (bh=32, qt=32)  [bh fastest -> balanced causal work across CUs]
// 256 threads = 4 independent waves, 16 q-rows each, KV tile 64.
// Swapped QK^T (mfma(K,Q)): lane owns scores for q=lane&15, k=(lane>>4)*4+r per
// 16-k fragment -- which is EXACTLY the B-operand layout of 16x16x16 MFMA, so
// P feeds PV straight from registers (no LDS round-trip, no shuffles).

__global__ __launch_bounds__(256) void k_attn(const short* __restrict__ Qb,
                                              const short* __restrict__ Kb,
                                              const short* __restrict__ Vt,
                                              short* __restrict__ Y) {
#if !HAVE_MFMA16
  __shared__ short plds[4][16][72];   // fallback: per-wave P tile
#endif
  __shared__ float ot[4][16][65];     // per-wave output transpose buffer
  const int bh = blockIdx.x, qt = blockIdx.y;
  const int b = bh >> 4, h = bh & 15;
  const int wave = threadIdx.x >> 6, lane = threadIdx.x & 63;
  const int qw = qt * 64 + wave * 16;
  const int ql = lane & 15, g = lane >> 4;
  const short* Qp = Qb + ((long)bh * 2048 + qw) * 64;
  const short* Kp = Kb + (long)bh * 2048 * 64;
  const short* Vp = Vt + (long)bh * 64 * 2048;

  const bf16x8 qf0 = *(const bf16x8*)(Qp + ql * 64 + g * 8);
  const bf16x8 qf1 = *(const bf16x8*)(Qp + ql * 64 + 32 + g * 8);

  f32x4 o[4];
#pragma unroll
  for (int df = 0; df < 4; ++df) o[df] = (f32x4){0.f, 0.f, 0.f, 0.f};
  float m = -1e30f, l = 0.f;
  const int qa = qw + ql;
  const int nt = (qw + 79) >> 6;      // tiles of 64 keys, covering k <= qw+15

  for (int t = 0; t < nt; ++t) {
    const int k0 = t * 64;
    // ---- QK^T: 8 independent MFMAs ----
    f32x4 z[4];
#pragma unroll
    for (int kf = 0; kf < 4; ++kf) {
      const short* Kr = Kp + (long)(k0 + kf * 16 + ql) * 64 + g * 8;
      const bf16x8 ka = *(const bf16x8*)Kr;
      const bf16x8 kb = *(const bf16x8*)(Kr + 32);
      f32x4 zz = (f32x4){0.f, 0.f, 0.f, 0.f};
      zz = MFMA(ka, qf0, zz);           // S^T[k][q], d 0..31
      zz = MFMA(kb, qf1, zz);           // += d 32..63
      z[kf] = zz;
    }
    float s[16];
    if (k0 + 63 <= qw) {                // tile fully below diagonal for whole wave
#pragma unroll
      for (int kf = 0; kf < 4; ++kf)
#pragma unroll
        for (int r = 0; r < 4; ++r) s[kf * 4 + r] = z[kf][r] * 0.125f;
    } else {
#pragma unroll
      for (int kf = 0; kf < 4; ++kf)
#pragma unroll
        for (int r = 0; r < 4; ++r) {
          const int kabs = k0 + kf * 16 + g * 4 + r;
          s[kf * 4 + r] = (kabs <= qa) ? z[kf][r] * 0.125f : -1e30f;
        }
    }
    // ---- online softmax (row q = ql lives on 4 lanes: g groups) ----
    float tmax = s[0];
#pragma unroll
    for (int j = 1; j < 16; ++j) tmax = fmaxf(tmax, s[j]);
    tmax = fmaxf(tmax, __shfl_xor(tmax, 16));
    tmax = fmaxf(tmax, __shfl_xor(tmax, 32));
    const float nm  = fmaxf(m, tmax);
    const float fac = __expf(m - nm);
    float p[16];
    float ts = 0.f;
#pragma unroll
    for (int j = 0; j < 16; ++j) { p[j] = __expf(s[j] - nm); ts += p[j]; }
    ts += __shfl_xor(ts, 16);
    ts += __shfl_xor(ts, 32);
    l = l * fac + ts;
    m = nm;
#pragma unroll
    for (int df = 0; df < 4; ++df) o[df] *= fac;

    // ---- PV ----
#if HAVE_MFMA16
    // P already sits in the 16x16x16 B-operand layout: k=(lane>>4)*4+r, col=ql.
#pragma unroll
    for (int kf = 0; kf < 4; ++kf) {
      s16x4 pk;
      pk[0] = f2bf(p[kf * 4 + 0]);
      pk[1] = f2bf(p[kf * 4 + 1]);
      pk[2] = f2bf(p[kf * 4 + 2]);
      pk[3] = f2bf(p[kf * 4 + 3]);
      const int kk = k0 + kf * 16 + g * 4;
#pragma unroll
      for (int df = 0; df < 4; ++df) {
        const s16x4 vk = *(const s16x4*)(Vp + (long)(df * 16 + ql) * 2048 + kk);
        o[df] = MFMA16(vk, pk, o[df]);  // O^T[d][q]
      }
    }
#else
    // fallback: P via LDS round-trip, PV as two 16x16x32 per df
#pragma unroll
    for (int kf = 0; kf < 4; ++kf) {
      s16x4 pk;
      pk[0] = f2bf(p[kf * 4 + 0]);
      pk[1] = f2bf(p[kf * 4 + 1]);
      pk[2] = f2bf(p[kf * 4 + 2]);
      pk[3] = f2bf(p[kf * 4 + 3]);
      *(s16x4*)&plds[wave][ql][kf * 16 + g * 4] = pk;
    }
    const bf16x8 pf0 = *(const bf16x8*)&plds[wave][ql][g * 8];
    const bf16x8 pf1 = *(const bf16x8*)&plds[wave][ql][32 + g * 8];
#pragma unroll
    for (int df = 0; df < 4; ++df) {
      const short* Vr = Vp + (long)(df * 16 + ql) * 2048 + k0;
      const bf16x8 vf0 = *(const bf16x8*)(Vr + g * 8);
      const bf16x8 vf1 = *(const bf16x8*)(Vr + 32 + g * 8);
      o[df] = MFMA(vf0, pf0, o[df]);
      o[df] = MFMA(vf1, pf1, o[df]);
    }
#endif
  }

  const float linv = 1.f / l;
#pragma unroll
  for (int df = 0; df < 4; ++df)
#pragma unroll
    for (int r = 0; r < 4; ++r)
      ot[wave][ql][df * 16 + g * 4 + r] = o[df][r] * linv;

  // transpose within wave, coalesced bf16 store
  const int q2 = lane >> 2, c4 = (lane & 3) * 16;
  short* Yp = Y + ((long)(b * 2048 + qw + q2)) * 1024 + h * 64 + c4;
  s16x8 y0, y1;
#pragma unroll
  for (int j = 0; j < 8; ++j) {
    y0[j] = f2bf(ot[wave][q2][c4 + j]);
    y1[j] = f2bf(ot[wave][q2][c4 + 8 + j]);
  }
  *(s16x8*)Yp = y0;
  *((s16x8*)(Yp + 8)) = y1;
}

// ---------------- launch ----------------

extern "C" void kernel_launch(void* const* d_in, const int* in_sizes, int n_in,
                              void* d_out, int out_size, void* d_ws, size_t ws_size,
                              hipStream_t stream) {
  const float* x      = (const float*)d_in[0];
  const float* W_attn = (const float*)d_in[1];
  const float* b_attn = (const float*)d_in[2];
  const float* W_proj = (const float*)d_in[3];
  const float* b_proj = (const float*)d_in[4];
  float* out = (float*)d_out;

  char* ws = (char*)d_ws;
  short* x_bf = (short*)(ws);                    //  8 MB  [4096][1024]
  short* Wt_a = (short*)(ws + 8388608);          //  6 MB  [3072][1024]
  short* Wt_p = (short*)(ws + 14680064);         //  2 MB  [1024][1024]
  short* Qb   = (short*)(ws + 16777216);         //  8 MB  [2,16,2048,64]
  short* Kb   = (short*)(ws + 25165824);         //  8 MB  [2,16,2048,64]
  short* Vtb  = (short*)(ws + 33554432);         //  8 MB  [2,16,64,2048]
  short* y_bf = (short*)(ws + 41943040);         //  8 MB  [4096][1024]

  k_f32_to_bf16<<<4096, 256, 0, stream>>>(x, x_bf, 4194304);
  k_transpose_bf<<<dim3(96, 32), 256, 0, stream>>>(W_attn, Wt_a, 1024, 3072);
  k_transpose_bf<<<dim3(32, 32), 256, 0, stream>>>(W_proj, Wt_p, 1024, 1024);
  k_gemm<0><<<dim3(24, 32), 256, 0, stream>>>(x_bf, Wt_a, b_attn, 4096, 3072, 1024,
                                              Qb, Kb, Vtb, nullptr);
  k_attn<<<dim3(32, 32), 256, 0, stream>>>(Qb, Kb, Vtb, y_bf);
  k_gemm<1><<<dim3(8, 32), 256, 0, stream>>>(y_bf, Wt_p, b_proj, 4096, 1024, 1024,
                                             nullptr, nullptr, nullptr, out);
}

// Round 3
// 267.086 us; speedup vs baseline: 1.1494x; 1.1136x over previous
//
#include <hip/hip_runtime.h>
#include <hip/hip_bf16.h>
#include <stdint.h>

// CausalSelfAttention: x[2,2048,1024] -> qkv -> 16-head causal attn -> proj.
// bf16 MFMA pipeline, fp32 accumulation everywhere.

typedef __attribute__((ext_vector_type(4))) float  f32x4;
typedef __attribute__((ext_vector_type(8))) __bf16 bf16x8;
typedef __attribute__((ext_vector_type(4))) short  s16x4;
typedef __attribute__((ext_vector_type(8))) short  s16x8;

#define MFMA(a, b, c) __builtin_amdgcn_mfma_f32_16x16x32_bf16((a), (b), (c), 0, 0, 0)

#if __has_builtin(__builtin_amdgcn_mfma_f32_16x16x16bf16_1k)
#define HAVE_MFMA16 1
#define MFMA16(a, b, c) __builtin_amdgcn_mfma_f32_16x16x16bf16_1k((a), (b), (c), 0, 0, 0)
#else
#define HAVE_MFMA16 0
#endif

__device__ __forceinline__ short f2bf(float x) {  // round-to-nearest-even f32->bf16
  union { float f; unsigned u; } v; v.f = x;
  unsigned r = v.u + 0x7FFFu + ((v.u >> 16) & 1u);
  return (short)(r >> 16);
}

__device__ __forceinline__ void gload16(const void* gptr, void* lptr) {
  __builtin_amdgcn_global_load_lds(
      (const __attribute__((address_space(1))) void*)gptr,
      (__attribute__((address_space(3))) void*)lptr, 16, 0, 0);
}

// ---------------- conversion kernels ----------------

__global__ __launch_bounds__(256) void k_f32_to_bf16(const float* __restrict__ in,
                                                     short* __restrict__ out, int n) {
  int i = (blockIdx.x * 256 + threadIdx.x) * 4;
  if (i >= n) return;
  float4 v = *(const float4*)(in + i);
  s16x4 o;
  o[0] = f2bf(v.x); o[1] = f2bf(v.y); o[2] = f2bf(v.z); o[3] = f2bf(v.w);
  *(s16x4*)(out + i) = o;
}

// W [R][C] fp32 row-major  ->  Wt [C][R] bf16 (i.e. [n][k] layout for GEMM B^T)
__global__ __launch_bounds__(256) void k_transpose_bf(const float* __restrict__ W,
                                                      short* __restrict__ Wt, int R, int C) {
  __shared__ float tile[32][33];
  const int tx = threadIdx.x & 31, ty = threadIdx.x >> 5;  // ty 0..7
  const int bx = blockIdx.x * 32, by = blockIdx.y * 32;
#pragma unroll
  for (int i = 0; i < 4; ++i)
    tile[ty + i * 8][tx] = W[(long)(by + ty + i * 8) * C + bx + tx];
  __syncthreads();
#pragma unroll
  for (int i = 0; i < 4; ++i)
    Wt[(long)(bx + ty + i * 8) * R + by + tx] = f2bf(tile[tx][ty + i * 8]);
}

// ---------------- GEMM: C[M][N] = A[M][K] * Bt[N][K]^T + bias ----------------
// 128x128 tile, BK=32, 4 waves (2x2 of 64x64), m97 2-barrier structure.
// EPI==0: scatter to Q[b,h,s,d], K[b,h,s,d], Vt[b,h,d,s] (bf16)
// EPI==1: fp32 row-major output

template <int EPI>
__global__ __launch_bounds__(256) void k_gemm(const short* __restrict__ A,
                                              const short* __restrict__ Bt,
                                              const float* __restrict__ bias,
                                              int M, int N, int K,
                                              short* __restrict__ q_out,
                                              short* __restrict__ k_out,
                                              short* __restrict__ vt_out,
                                              float* __restrict__ c_out) {
  __shared__ short As[128 * 32];
  __shared__ short Bs[128 * 32];
  const int tid  = threadIdx.x;
  const int lane = tid & 63;
  const int wave = tid >> 6;
  const int wm = (wave >> 1) * 64, wn = (wave & 1) * 64;
  const int bm = blockIdx.y * 128, bn = blockIdx.x * 128;
  const int sr = tid >> 2, sc = (tid & 3) * 8;
  const short* Ag = A + (long)(bm + sr) * K + sc;
  const short* Bg = Bt + (long)(bn + sr) * K + sc;
  short* Asl = As + tid * 8;
  short* Bsl = Bs + tid * 8;
  const int fr = lane & 15, fg = lane >> 4;

  f32x4 acc[4][4];
#pragma unroll
  for (int i = 0; i < 4; ++i)
#pragma unroll
    for (int j = 0; j < 4; ++j) acc[i][j] = (f32x4){0.f, 0.f, 0.f, 0.f};

  for (int kt = 0; kt < K; kt += 32) {
    gload16(Ag + kt, Asl);
    gload16(Ag + kt + 64 * K, Asl + 2048);
    gload16(Bg + kt, Bsl);
    gload16(Bg + kt + 64 * K, Bsl + 2048);
    __syncthreads();  // drains vmcnt: staged data visible
    bf16x8 af[4], bfr[4];
    const short* Ar = As + (wm + fr) * 32 + fg * 8;
    const short* Br = Bs + (wn + fr) * 32 + fg * 8;
#pragma unroll
    for (int mi = 0; mi < 4; ++mi) af[mi] = *(const bf16x8*)(Ar + mi * 16 * 32);
#pragma unroll
    for (int ni = 0; ni < 4; ++ni) bfr[ni] = *(const bf16x8*)(Br + ni * 16 * 32);
#pragma unroll
    for (int mi = 0; mi < 4; ++mi)
#pragma unroll
      for (int ni = 0; ni < 4; ++ni)
        acc[mi][ni] = MFMA(af[mi], bfr[ni], acc[mi][ni]);
    __syncthreads();  // compute done before next-tile overwrite
  }

#pragma unroll
  for (int mi = 0; mi < 4; ++mi) {
#pragma unroll
    for (int ni = 0; ni < 4; ++ni) {
      const int gcol  = bn + wn + ni * 16 + fr;
      const float bv  = bias[gcol];
      const int grow0 = bm + wm + mi * 16 + fg * 4;
      if (EPI == 0) {
        const int which = gcol >> 10;       // uniform per block (BN=128 within 1024)
        const int e = gcol & 1023;
        const int h = e >> 6, d = e & 63;
#pragma unroll
        for (int r = 0; r < 4; ++r) {
          const int mrow = grow0 + r;
          const int b = mrow >> 11, s = mrow & 2047;
          const short val = f2bf(acc[mi][ni][r] + bv);
          if (which == 0)      q_out[((long)(b * 16 + h) * 2048 + s) * 64 + d] = val;
          else if (which == 1) k_out[((long)(b * 16 + h) * 2048 + s) * 64 + d] = val;
          else                 vt_out[((long)(b * 16 + h) * 64 + d) * 2048 + s] = val;
        }
      } else {
#pragma unroll
        for (int r = 0; r < 4; ++r)
          c_out[(long)(grow0 + r) * N + gcol] = acc[mi][ni][r] + bv;
      }
    }
  }
}

// ---------------- causal flash attention ----------------
// grid (bh=32, 128 strips of 16 q-rows), 64-thread blocks (ONE wave) ->
// 4096 independent blocks, dynamically balanced; strip reversed so heavy
// blocks dispatch first (LPT). Swapped QK^T (mfma(K,Q)): lane owns scores
// for q=lane&15, k=(lane>>4)*4+r per 16-k fragment == B-operand layout of
// 16x16x16 MFMA, so P feeds PV from registers. K prefetched for t+1 and V
// prefetched before softmax; softmax in exp2 domain, tree reductions,
// defer-max rescale (THR=8 in log2 domain).

__global__ __launch_bounds__(64) void k_attn(const short* __restrict__ Qb,
                                             const short* __restrict__ Kb,
                                             const short* __restrict__ Vt,
                                             short* __restrict__ Y) {
  __shared__ float ot[16][65];
  const int bh = blockIdx.x;            // 0..31
  const int strip = 127 - blockIdx.y;   // heavy-first dispatch
  const int qw = strip * 16;
  const int b = bh >> 4, h = bh & 15;
  const int lane = threadIdx.x;
  const int ql = lane & 15, g = lane >> 4;
  const short* Qp = Qb + ((long)bh * 2048 + qw) * 64;
  const short* Kp = Kb + (long)bh * 2048 * 64;
  const short* Vp = Vt + (long)bh * 64 * 2048;

  const bf16x8 qf0 = *(const bf16x8*)(Qp + ql * 64 + g * 8);
  const bf16x8 qf1 = *(const bf16x8*)(Qp + ql * 64 + 32 + g * 8);

  f32x4 o[4];
#pragma unroll
  for (int df = 0; df < 4; ++df) o[df] = (f32x4){0.f, 0.f, 0.f, 0.f};
  float m = -1e30f, l = 0.f;
  const int qa = qw + ql;
  const int nt = (qw + 79) >> 6;        // 64-key tiles covering k <= qw+15
  const float SC = 0.125f * 1.44269504088896341f;  // (1/sqrt(64)) * log2(e)

  bf16x8 ka[4], kb[4];
#pragma unroll
  for (int kf = 0; kf < 4; ++kf) {      // preload K tile t=0
    const short* Kr = Kp + (long)(kf * 16 + ql) * 64 + g * 8;
    ka[kf] = *(const bf16x8*)Kr;
    kb[kf] = *(const bf16x8*)(Kr + 32);
  }

  for (int t = 0; t < nt; ++t) {
    const int k0 = t * 64;
    // ---- QK^T: 8 independent MFMAs (consume K regs) ----
    f32x4 z[4];
#pragma unroll
    for (int kf = 0; kf < 4; ++kf) {
      f32x4 zz = (f32x4){0.f, 0.f, 0.f, 0.f};
      zz = MFMA(ka[kf], qf0, zz);       // S^T[k][q], d 0..31
      zz = MFMA(kb[kf], qf1, zz);       // += d 32..63
      z[kf] = zz;
    }
    // ---- prefetch K tile t+1 (hidden under softmax+PV) ----
    if (t + 1 < nt) {
      const int kn = k0 + 64;
#pragma unroll
      for (int kf = 0; kf < 4; ++kf) {
        const short* Kr = Kp + (long)(kn + kf * 16 + ql) * 64 + g * 8;
        ka[kf] = *(const bf16x8*)Kr;
        kb[kf] = *(const bf16x8*)(Kr + 32);
      }
    }
    // ---- prefetch V tile t (hidden under softmax) ----
    s16x4 v0[4], v1[4], v2[4], v3[4];
#pragma unroll
    for (int df = 0; df < 4; ++df) {
      const short* Vr = Vp + (long)(df * 16 + ql) * 2048 + k0 + g * 4;
      v0[df] = *(const s16x4*)(Vr);
      v1[df] = *(const s16x4*)(Vr + 16);
      v2[df] = *(const s16x4*)(Vr + 32);
      v3[df] = *(const s16x4*)(Vr + 48);
    }
    // ---- mask + scale (exp2 domain) ----
    float s[16];
    if (k0 + 63 <= qw) {                // tile fully below diagonal
#pragma unroll
      for (int kf = 0; kf < 4; ++kf)
#pragma unroll
        for (int r = 0; r < 4; ++r) s[kf * 4 + r] = z[kf][r] * SC;
    } else {
#pragma unroll
      for (int kf = 0; kf < 4; ++kf)
#pragma unroll
        for (int r = 0; r < 4; ++r) {
          const int kabs = k0 + kf * 16 + g * 4 + r;
          s[kf * 4 + r] = (kabs <= qa) ? z[kf][r] * SC : -1e30f;
        }
    }
    // ---- tree max (depth 4) + 2 shfl ----
    float mx[8];
#pragma unroll
    for (int j = 0; j < 8; ++j) mx[j] = fmaxf(s[j], s[j + 8]);
#pragma unroll
    for (int j = 0; j < 4; ++j) mx[j] = fmaxf(mx[j], mx[j + 4]);
    float tmax = fmaxf(fmaxf(mx[0], mx[2]), fmaxf(mx[1], mx[3]));
    tmax = fmaxf(tmax, __shfl_xor(tmax, 16));
    tmax = fmaxf(tmax, __shfl_xor(tmax, 32));
    // ---- defer-max rescale (T13): skip o-rescale unless max grew > 8 ----
    if (!__all(tmax <= m + 8.0f)) {
      const float nm = fmaxf(m, tmax);
      const float fac = exp2f(m - nm);
      l *= fac;
#pragma unroll
      for (int df = 0; df < 4; ++df) o[df] *= fac;
      m = nm;
    }
    // ---- exp + tree sum ----
    float p[16];
#pragma unroll
    for (int j = 0; j < 16; ++j) p[j] = exp2f(s[j] - m);
    float sm[8];
#pragma unroll
    for (int j = 0; j < 8; ++j) sm[j] = p[j] + p[j + 8];
#pragma unroll
    for (int j = 0; j < 4; ++j) sm[j] += sm[j + 4];
    float ts = (sm[0] + sm[1]) + (sm[2] + sm[3]);
    ts += __shfl_xor(ts, 16);
    ts += __shfl_xor(ts, 32);
    l += ts;
    // ---- pack P, PV from registers ----
#if HAVE_MFMA16
    s16x4 pk0, pk1, pk2, pk3;
    pk0[0]=f2bf(p[0]);  pk0[1]=f2bf(p[1]);  pk0[2]=f2bf(p[2]);  pk0[3]=f2bf(p[3]);
    pk1[0]=f2bf(p[4]);  pk1[1]=f2bf(p[5]);  pk1[2]=f2bf(p[6]);  pk1[3]=f2bf(p[7]);
    pk2[0]=f2bf(p[8]);  pk2[1]=f2bf(p[9]);  pk2[2]=f2bf(p[10]); pk2[3]=f2bf(p[11]);
    pk3[0]=f2bf(p[12]); pk3[1]=f2bf(p[13]); pk3[2]=f2bf(p[14]); pk3[3]=f2bf(p[15]);
#pragma unroll
    for (int df = 0; df < 4; ++df) {
      o[df] = MFMA16(v0[df], pk0, o[df]);   // O^T[d][q]
      o[df] = MFMA16(v1[df], pk1, o[df]);
      o[df] = MFMA16(v2[df], pk2, o[df]);
      o[df] = MFMA16(v3[df], pk3, o[df]);
    }
#else
    // fallback: pair k-fragments into 16x16x32 via bf16x8 built from two s16x4
#pragma unroll
    for (int df = 0; df < 4; ++df) {
      union { s16x8 s8; bf16x8 b8; } va, vb;
      union { s16x8 s8; } pa, pb;
#pragma unroll
      for (int j = 0; j < 4; ++j) {
        va.s8[j] = v0[df][j]; va.s8[j + 4] = v1[df][j];
        vb.s8[j] = v2[df][j]; vb.s8[j + 4] = v3[df][j];
        pa.s8[j] = f2bf(p[j]);      pa.s8[j + 4] = f2bf(p[4 + j]);
        pb.s8[j] = f2bf(p[8 + j]);  pb.s8[j + 4] = f2bf(p[12 + j]);
      }
      o[df] = MFMA(va.b8, *(bf16x8*)&pa, o[df]);
      o[df] = MFMA(vb.b8, *(bf16x8*)&pb, o[df]);
    }
#endif
  }

  // ---- epilogue: divide, transpose via LDS, coalesced store ----
  const float linv = 1.f / l;
#pragma unroll
  for (int df = 0; df < 4; ++df)
#pragma unroll
    for (int r = 0; r < 4; ++r)
      ot[ql][df * 16 + g * 4 + r] = o[df][r] * linv;
  __syncthreads();
  const int q2 = lane >> 2, c4 = (lane & 3) * 16;
  short* Yp = Y + ((long)(b * 2048 + qw + q2)) * 1024 + h * 64 + c4;
  s16x8 y0, y1;
#pragma unroll
  for (int j = 0; j < 8; ++j) {
    y0[j] = f2bf(ot[q2][c4 + j]);
    y1[j] = f2bf(ot[q2][c4 + 8 + j]);
  }
  *(s16x8*)Yp = y0;
  *((s16x8*)(Yp + 8)) = y1;
}

// ---------------- launch ----------------

extern "C" void kernel_launch(void* const* d_in, const int* in_sizes, int n_in,
                              void* d_out, int out_size, void* d_ws, size_t ws_size,
                              hipStream_t stream) {
  const float* x      = (const float*)d_in[0];
  const float* W_attn = (const float*)d_in[1];
  const float* b_attn = (const float*)d_in[2];
  const float* W_proj = (const float*)d_in[3];
  const float* b_proj = (const float*)d_in[4];
  float* out = (float*)d_out;

  char* ws = (char*)d_ws;
  short* x_bf = (short*)(ws);                    //  8 MB  [4096][1024]
  short* Wt_a = (short*)(ws + 8388608);          //  6 MB  [3072][1024]
  short* Wt_p = (short*)(ws + 14680064);         //  2 MB  [1024][1024]
  short* Qb   = (short*)(ws + 16777216);         //  8 MB  [2,16,2048,64]
  short* Kb   = (short*)(ws + 25165824);         //  8 MB  [2,16,2048,64]
  short* Vtb  = (short*)(ws + 33554432);         //  8 MB  [2,16,64,2048]
  short* y_bf = (short*)(ws + 41943040);         //  8 MB  [4096][1024]

  k_f32_to_bf16<<<4096, 256, 0, stream>>>(x, x_bf, 4194304);
  k_transpose_bf<<<dim3(96, 32), 256, 0, stream>>>(W_attn, Wt_a, 1024, 3072);
  k_transpose_bf<<<dim3(32, 32), 256, 0, stream>>>(W_proj, Wt_p, 1024, 1024);
  k_gemm<0><<<dim3(24, 32), 256, 0, stream>>>(x_bf, Wt_a, b_attn, 4096, 3072, 1024,
                                              Qb, Kb, Vtb, nullptr);
  k_attn<<<dim3(32, 128), 64, 0, stream>>>(Qb, Kb, Vtb, y_bf);
  k_gemm<1><<<dim3(8, 32), 256, 0, stream>>>(y_bf, Wt_p, b_proj, 4096, 1024, 1024,
                                             nullptr, nullptr, nullptr, out);
}

// Round 5
// 135.502 us; speedup vs baseline: 2.2656x; 1.9711x over previous
//
#include <hip/hip_runtime.h>
#include <hip/hip_bf16.h>
#include <stdint.h>

// CausalSelfAttention: x[2,2048,1024] -> qkv -> 16-head causal attn -> proj.
// bf16 MFMA pipeline, fp32 accumulation everywhere.

typedef __attribute__((ext_vector_type(4))) float  f32x4;
typedef __attribute__((ext_vector_type(8))) __bf16 bf16x8;
typedef __attribute__((ext_vector_type(4))) short  s16x4;
typedef __attribute__((ext_vector_type(8))) short  s16x8;

#define MFMA(a, b, c) __builtin_amdgcn_mfma_f32_16x16x32_bf16((a), (b), (c), 0, 0, 0)

// 16x16x16 bf16 MFMA: present in the DEVICE pass on gfx950 (rounds 2-3 ran it);
// __has_builtin is false in the HOST pass, which only parses device bodies ->
// give the host a parse-only stub.
#if defined(__HIP_DEVICE_COMPILE__)
#define MFMA16(a, b, c) __builtin_amdgcn_mfma_f32_16x16x16bf16_1k((a), (b), (c), 0, 0, 0)
#else
#define MFMA16(a, b, c) (c)
#endif

__device__ __forceinline__ short f2bf(float x) {  // round-to-nearest-even f32->bf16
  union { float f; unsigned u; } v; v.f = x;
  unsigned r = v.u + 0x7FFFu + ((v.u >> 16) & 1u);
  return (short)(r >> 16);
}

__device__ __forceinline__ void gload16(const void* gptr, void* lptr) {
  __builtin_amdgcn_global_load_lds(
      (const __attribute__((address_space(1))) void*)gptr,
      (__attribute__((address_space(3))) void*)lptr, 16, 0, 0);
}

// ---------------- conversion kernels ----------------

__global__ __launch_bounds__(256) void k_f32_to_bf16(const float* __restrict__ in,
                                                     short* __restrict__ out, int n) {
  int i = (blockIdx.x * 256 + threadIdx.x) * 4;
  if (i >= n) return;
  float4 v = *(const float4*)(in + i);
  s16x4 o;
  o[0] = f2bf(v.x); o[1] = f2bf(v.y); o[2] = f2bf(v.z); o[3] = f2bf(v.w);
  *(s16x4*)(out + i) = o;
}

// W [R][C] fp32 row-major  ->  Wt [C][R] bf16 (i.e. [n][k] layout for GEMM B^T)
__global__ __launch_bounds__(256) void k_transpose_bf(const float* __restrict__ W,
                                                      short* __restrict__ Wt, int R, int C) {
  __shared__ float tile[32][33];
  const int tx = threadIdx.x & 31, ty = threadIdx.x >> 5;  // ty 0..7
  const int bx = blockIdx.x * 32, by = blockIdx.y * 32;
#pragma unroll
  for (int i = 0; i < 4; ++i)
    tile[ty + i * 8][tx] = W[(long)(by + ty + i * 8) * C + bx + tx];
  __syncthreads();
#pragma unroll
  for (int i = 0; i < 4; ++i)
    Wt[(long)(bx + ty + i * 8) * R + by + tx] = f2bf(tile[tx][ty + i * 8]);
}

// ---------------- GEMM: C[M][N] = A[M][K] * Bt[N][K]^T + bias ----------------
// 128x128 tile, BK=32, 4 waves (2x2 of 64x64), m97 2-barrier structure.
// EPI==0: scatter to Q[b,h,s,d], K[b,h,s,d], Vt[b,h,d,s] (bf16)
// EPI==1: fp32 row-major output

template <int EPI>
__global__ __launch_bounds__(256) void k_gemm(const short* __restrict__ A,
                                              const short* __restrict__ Bt,
                                              const float* __restrict__ bias,
                                              int M, int N, int K,
                                              short* __restrict__ q_out,
                                              short* __restrict__ k_out,
                                              short* __restrict__ vt_out,
                                              float* __restrict__ c_out) {
  __shared__ short As[128 * 32];
  __shared__ short Bs[128 * 32];
  const int tid  = threadIdx.x;
  const int lane = tid & 63;
  const int wave = tid >> 6;
  const int wm = (wave >> 1) * 64, wn = (wave & 1) * 64;
  const int bm = blockIdx.y * 128, bn = blockIdx.x * 128;
  const int sr = tid >> 2, sc = (tid & 3) * 8;
  const short* Ag = A + (long)(bm + sr) * K + sc;
  const short* Bg = Bt + (long)(bn + sr) * K + sc;
  short* Asl = As + tid * 8;
  short* Bsl = Bs + tid * 8;
  const int fr = lane & 15, fg = lane >> 4;

  f32x4 acc[4][4];
#pragma unroll
  for (int i = 0; i < 4; ++i)
#pragma unroll
    for (int j = 0; j < 4; ++j) acc[i][j] = (f32x4){0.f, 0.f, 0.f, 0.f};

  for (int kt = 0; kt < K; kt += 32) {
    gload16(Ag + kt, Asl);
    gload16(Ag + kt + 64 * K, Asl + 2048);
    gload16(Bg + kt, Bsl);
    gload16(Bg + kt + 64 * K, Bsl + 2048);
    __syncthreads();  // drains vmcnt: staged data visible
    bf16x8 af[4], bfr[4];
    const short* Ar = As + (wm + fr) * 32 + fg * 8;
    const short* Br = Bs + (wn + fr) * 32 + fg * 8;
#pragma unroll
    for (int mi = 0; mi < 4; ++mi) af[mi] = *(const bf16x8*)(Ar + mi * 16 * 32);
#pragma unroll
    for (int ni = 0; ni < 4; ++ni) bfr[ni] = *(const bf16x8*)(Br + ni * 16 * 32);
#pragma unroll
    for (int mi = 0; mi < 4; ++mi)
#pragma unroll
      for (int ni = 0; ni < 4; ++ni)
        acc[mi][ni] = MFMA(af[mi], bfr[ni], acc[mi][ni]);
    __syncthreads();  // compute done before next-tile overwrite
  }

#pragma unroll
  for (int mi = 0; mi < 4; ++mi) {
#pragma unroll
    for (int ni = 0; ni < 4; ++ni) {
      const int gcol  = bn + wn + ni * 16 + fr;
      const float bv  = bias[gcol];
      const int grow0 = bm + wm + mi * 16 + fg * 4;
      if (EPI == 0) {
        const int which = gcol >> 10;       // uniform per block (BN=128 within 1024)
        const int e = gcol & 1023;
        const int h = e >> 6, d = e & 63;
#pragma unroll
        for (int r = 0; r < 4; ++r) {
          const int mrow = grow0 + r;
          const int b = mrow >> 11, s = mrow & 2047;
          const short val = f2bf(acc[mi][ni][r] + bv);
          if (which == 0)      q_out[((long)(b * 16 + h) * 2048 + s) * 64 + d] = val;
          else if (which == 1) k_out[((long)(b * 16 + h) * 2048 + s) * 64 + d] = val;
          else                 vt_out[((long)(b * 16 + h) * 64 + d) * 2048 + s] = val;
        }
      } else {
#pragma unroll
        for (int r = 0; r < 4; ++r)
          c_out[(long)(grow0 + r) * N + gcol] = acc[mi][ni][r] + bv;
      }
    }
  }
}

// ---------------- causal flash attention ----------------
// grid (bh=32, 32 strips of 64 q-rows), 256-thread blocks (4 waves x 16 rows).
// K/V tiles (64 keys) staged into XOR-swizzled LDS once per block via async
// global_load_lds (double-buffered; stage issued AFTER the barrier so tile
// t+1's vmcnt drain hides under tile t's compute) -> ~12x fewer L1 line
// requests per q-row than private register loads.
// Swizzle (T2, rule #21): LDS row r keeps 16B-chunk slot j = c ^ (r&7) via
// pre-swizzled global source; fragment reads apply the same XOR -> <=2-way.
// Swapped QK^T (mfma(K,Q)) puts P in the 16x16x16 B-operand layout -> PV
// straight from registers. Last (diagonal) tile: wave w only needs kf<=w.

__global__ __launch_bounds__(256, 4) void k_attn(const short* __restrict__ Qb,
                                                 const short* __restrict__ Kb,
                                                 const short* __restrict__ Vt,
                                                 short* __restrict__ Y) {
  __shared__ short smem[2][2][4096];   // [buf][0=K,1=V][64 rows][64 shorts]
  const int bh = blockIdx.x;
  const int strip = 31 - blockIdx.y;   // heavy-first dispatch
  const int qw0 = strip * 64;
  const int b = bh >> 4, h = bh & 15;
  const int tid = threadIdx.x;
  const int w = tid >> 6, lane = tid & 63;
  const int ql = lane & 15, g = lane >> 4;
  const short* Kp = Kb + (long)bh * 2048 * 64;
  const short* Vp = Vt + (long)bh * 64 * 2048;
  const short* Qp = Qb + ((long)bh * 2048 + qw0 + w * 16) * 64;

  const bf16x8 qf0 = *(const bf16x8*)(Qp + ql * 64 + g * 8);
  const bf16x8 qf1 = *(const bf16x8*)(Qp + ql * 64 + 32 + g * 8);

  // staging geometry: thread i covers row r=j*32+(i>>3), chunk slot i&7;
  // source chunk c = (i&7) ^ (r&7)  (inverse-swizzled source, linear dest)
  const int sr_ = tid >> 3, sj_ = tid & 7;

  f32x4 o[4];
#pragma unroll
  for (int df = 0; df < 4; ++df) o[df] = (f32x4){0.f, 0.f, 0.f, 0.f};
  float m = -1e30f, l = 0.f;
  const int nt = strip + 1;
  const float SC = 0.125f * 1.44269504088896341f;  // (1/sqrt(64)) * log2(e)

  {  // prologue stage of tile 0
#pragma unroll
    for (int j = 0; j < 2; ++j) {
      const int r = j * 32 + sr_;
      const int c = sj_ ^ (r & 7);
      gload16(Kp + (long)r * 64 + c * 8, &smem[0][0][j * 2048 + tid * 8]);
      gload16(Vp + (long)r * 2048 + c * 8, &smem[0][1][j * 2048 + tid * 8]);
    }
  }

  for (int t = 0; t < nt; ++t) {
    const int cur = t & 1;
    __syncthreads();                  // waits own vmcnt -> buf[cur] ready, prev reads done
    if (t + 1 < nt) {                 // issue next-tile stage; lands before next barrier
      const int k0n = (t + 1) * 64;
#pragma unroll
      for (int j = 0; j < 2; ++j) {
        const int r = j * 32 + sr_;
        const int c = sj_ ^ (r & 7);
        gload16(Kp + (long)(k0n + r) * 64 + c * 8, &smem[cur ^ 1][0][j * 2048 + tid * 8]);
        gload16(Vp + (long)r * 2048 + k0n + c * 8, &smem[cur ^ 1][1][j * 2048 + tid * 8]);
      }
    }
    const short* Kl = &smem[cur][0][0];
    const short* Vl = &smem[cur][1][0];
    const int kfcap = (t == strip) ? (w + 1) : 4;   // wave-uniform

    // ---- QK^T from LDS (swizzled b128 reads) ----
    float s[16];
#pragma unroll
    for (int j = 0; j < 16; ++j) s[j] = -1e30f;
#pragma unroll
    for (int kf = 0; kf < 4; ++kf) {
      if (kf < kfcap) {
        const int r = kf * 16 + ql;
        const bf16x8 ka = *(const bf16x8*)(Kl + r * 64 + ((g ^ (r & 7)) * 8));
        const bf16x8 kb = *(const bf16x8*)(Kl + r * 64 + (((4 + g) ^ (r & 7)) * 8));
        f32x4 zz = (f32x4){0.f, 0.f, 0.f, 0.f};
        zz = MFMA(ka, qf0, zz);       // S^T[k][q], d 0..31
        zz = MFMA(kb, qf1, zz);       // += d 32..63
        if (t < strip || kf < w) {
#pragma unroll
          for (int r4 = 0; r4 < 4; ++r4) s[kf * 4 + r4] = zz[r4] * SC;
        } else {                      // kf == w: diagonal 16x16 block
#pragma unroll
          for (int r4 = 0; r4 < 4; ++r4)
            s[kf * 4 + r4] = (g * 4 + r4 <= ql) ? zz[r4] * SC : -1e30f;
        }
      }
    }
    // ---- tree max + 2 shfl ----
    float mx[8];
#pragma unroll
    for (int j = 0; j < 8; ++j) mx[j] = fmaxf(s[j], s[j + 8]);
#pragma unroll
    for (int j = 0; j < 4; ++j) mx[j] = fmaxf(mx[j], mx[j + 4]);
    float tmax = fmaxf(fmaxf(mx[0], mx[2]), fmaxf(mx[1], mx[3]));
    tmax = fmaxf(tmax, __shfl_xor(tmax, 16));
    tmax = fmaxf(tmax, __shfl_xor(tmax, 32));
    // ---- defer-max rescale (T13, log2 domain THR=8) ----
    if (!__all(tmax <= m + 8.0f)) {
      const float nm = fmaxf(m, tmax);
      const float fac = exp2f(m - nm);
      l *= fac;
#pragma unroll
      for (int df = 0; df < 4; ++df) o[df] *= fac;
      m = nm;
    }
    // ---- exp + tree sum ----
    float p[16];
#pragma unroll
    for (int j = 0; j < 16; ++j) p[j] = exp2f(s[j] - m);
    float sm[8];
#pragma unroll
    for (int j = 0; j < 8; ++j) sm[j] = p[j] + p[j + 8];
#pragma unroll
    for (int j = 0; j < 4; ++j) sm[j] += sm[j + 4];
    float ts = (sm[0] + sm[1]) + (sm[2] + sm[3]);
    ts += __shfl_xor(ts, 16);
    ts += __shfl_xor(ts, 32);
    l += ts;
    // ---- PV from registers + swizzled V b64 reads ----
#pragma unroll
    for (int kf = 0; kf < 4; ++kf) {
      if (kf < kfcap) {
        s16x4 pk;
        pk[0] = f2bf(p[kf * 4 + 0]);
        pk[1] = f2bf(p[kf * 4 + 1]);
        pk[2] = f2bf(p[kf * 4 + 2]);
        pk[3] = f2bf(p[kf * 4 + 3]);
#pragma unroll
        for (int df = 0; df < 4; ++df) {
          const int d = df * 16 + ql;
          const int c = kf * 2 + (g >> 1);
          const s16x4 vk = *(const s16x4*)(Vl + d * 64 + ((c ^ (d & 7)) * 8) + (g & 1) * 4);
          o[df] = MFMA16(vk, pk, o[df]);   // O^T[d][q]
        }
      }
    }
  }

  // ---- epilogue: divide, transpose via LDS overlay, coalesced store ----
  __syncthreads();                    // all waves done reading K/V buffers
  float* ot = (float*)&smem[0][0][0] + w * 1040;   // per-wave 16x65 floats
  const float linv = 1.f / l;
#pragma unroll
  for (int df = 0; df < 4; ++df)
#pragma unroll
    for (int r = 0; r < 4; ++r)
      ot[ql * 65 + df * 16 + g * 4 + r] = o[df][r] * linv;
  const int q2 = lane >> 2, c4 = (lane & 3) * 16;
  short* Yp = Y + ((long)(b * 2048 + qw0 + w * 16 + q2)) * 1024 + h * 64 + c4;
  s16x8 y0, y1;
#pragma unroll
  for (int j = 0; j < 8; ++j) {
    y0[j] = f2bf(ot[q2 * 65 + c4 + j]);
    y1[j] = f2bf(ot[q2 * 65 + c4 + 8 + j]);
  }
  *(s16x8*)Yp = y0;
  *((s16x8*)(Yp + 8)) = y1;
}

// ---------------- launch ----------------

extern "C" void kernel_launch(void* const* d_in, const int* in_sizes, int n_in,
                              void* d_out, int out_size, void* d_ws, size_t ws_size,
                              hipStream_t stream) {
  const float* x      = (const float*)d_in[0];
  const float* W_attn = (const float*)d_in[1];
  const float* b_attn = (const float*)d_in[2];
  const float* W_proj = (const float*)d_in[3];
  const float* b_proj = (const float*)d_in[4];
  float* out = (float*)d_out;

  char* ws = (char*)d_ws;
  short* x_bf = (short*)(ws);                    //  8 MB  [4096][1024]
  short* Wt_a = (short*)(ws + 8388608);          //  6 MB  [3072][1024]
  short* Wt_p = (short*)(ws + 14680064);         //  2 MB  [1024][1024]
  short* Qb   = (short*)(ws + 16777216);         //  8 MB  [2,16,2048,64]
  short* Kb   = (short*)(ws + 25165824);         //  8 MB  [2,16,2048,64]
  short* Vtb  = (short*)(ws + 33554432);         //  8 MB  [2,16,64,2048]
  short* y_bf = (short*)(ws + 41943040);         //  8 MB  [4096][1024]

  k_f32_to_bf16<<<4096, 256, 0, stream>>>(x, x_bf, 4194304);
  k_transpose_bf<<<dim3(96, 32), 256, 0, stream>>>(W_attn, Wt_a, 1024, 3072);
  k_transpose_bf<<<dim3(32, 32), 256, 0, stream>>>(W_proj, Wt_p, 1024, 1024);
  k_gemm<0><<<dim3(24, 32), 256, 0, stream>>>(x_bf, Wt_a, b_attn, 4096, 3072, 1024,
                                              Qb, Kb, Vtb, nullptr);
  k_attn<<<dim3(32, 32), 256, 0, stream>>>(Qb, Kb, Vtb, y_bf);
  k_gemm<1><<<dim3(8, 32), 256, 0, stream>>>(y_bf, Wt_p, b_proj, 4096, 1024, 1024,
                                             nullptr, nullptr, nullptr, out);
}

// Round 6
// 129.061 us; speedup vs baseline: 2.3787x; 1.0499x over previous
//
#include <hip/hip_runtime.h>
#include <hip/hip_bf16.h>
#include <stdint.h>

// CausalSelfAttention: x[2,2048,1024] -> qkv -> 16-head causal attn -> proj.
// bf16 MFMA pipeline, fp32 accumulation everywhere.

typedef __attribute__((ext_vector_type(4))) float  f32x4;
typedef __attribute__((ext_vector_type(8))) __bf16 bf16x8;
typedef __attribute__((ext_vector_type(4))) short  s16x4;
typedef __attribute__((ext_vector_type(8))) short  s16x8;

#define MFMA(a, b, c) __builtin_amdgcn_mfma_f32_16x16x32_bf16((a), (b), (c), 0, 0, 0)

// 16x16x16 bf16 MFMA: device pass has it on gfx950; host pass only parses.
#if defined(__HIP_DEVICE_COMPILE__)
#define MFMA16(a, b, c) __builtin_amdgcn_mfma_f32_16x16x16bf16_1k((a), (b), (c), 0, 0, 0)
#else
#define MFMA16(a, b, c) (c)
#endif

// f32 -> bf16 RTNE. Device: native cast so the compiler can fuse pairs into
// v_cvt_pk_bf16_f32 (m240: scalar casts compile well; manual bit-twiddle
// blocks the fusion). Host: parse-only bit-twiddle equivalent.
__device__ __forceinline__ short f2bf(float x) {
#if defined(__HIP_DEVICE_COMPILE__)
  union { __bf16 b; short s; } u; u.b = (__bf16)x; return u.s;
#else
  union { float f; unsigned u; } v; v.f = x;
  unsigned r = v.u + 0x7FFFu + ((v.u >> 16) & 1u);
  return (short)(r >> 16);
#endif
}

__device__ __forceinline__ void gload16(const void* gptr, void* lptr) {
  __builtin_amdgcn_global_load_lds(
      (const __attribute__((address_space(1))) void*)gptr,
      (__attribute__((address_space(3))) void*)lptr, 16, 0, 0);
}

// ---------------- conversion kernels ----------------

__global__ __launch_bounds__(256) void k_f32_to_bf16(const float* __restrict__ in,
                                                     short* __restrict__ out, int n) {
  int i = (blockIdx.x * 256 + threadIdx.x) * 4;
  if (i >= n) return;
  float4 v = *(const float4*)(in + i);
  s16x4 o;
  o[0] = f2bf(v.x); o[1] = f2bf(v.y); o[2] = f2bf(v.z); o[3] = f2bf(v.w);
  *(s16x4*)(out + i) = o;
}

// W [R][C] fp32 row-major  ->  Wt [C][R] bf16 (i.e. [n][k] layout for GEMM B^T)
__global__ __launch_bounds__(256) void k_transpose_bf(const float* __restrict__ W,
                                                      short* __restrict__ Wt, int R, int C) {
  __shared__ float tile[32][33];
  const int tx = threadIdx.x & 31, ty = threadIdx.x >> 5;  // ty 0..7
  const int bx = blockIdx.x * 32, by = blockIdx.y * 32;
#pragma unroll
  for (int i = 0; i < 4; ++i)
    tile[ty + i * 8][tx] = W[(long)(by + ty + i * 8) * C + bx + tx];
  __syncthreads();
#pragma unroll
  for (int i = 0; i < 4; ++i)
    Wt[(long)(bx + ty + i * 8) * R + by + tx] = f2bf(tile[tx][ty + i * 8]);
}

// ---------------- GEMM: C[M][N] = A[M][K] * Bt[N][K]^T + bias ----------------
// 128x128 tile, BK=32, 4 waves (2x2 of 64x64). 2-phase double-buffered LDS
// (T3-minimum): barrier -> issue stage(t+1) -> compute(t); the next-tile load
// drains at the NEXT barrier, hidden under this tile's compute. One barrier
// per K-step.
// EPI==0: scatter to Q[b,h,s,d], K[b,h,s,d], Vt[b,h,d,s] (bf16)
// EPI==1: fp32 row-major output

template <int EPI>
__global__ __launch_bounds__(256) void k_gemm(const short* __restrict__ A,
                                              const short* __restrict__ Bt,
                                              const float* __restrict__ bias,
                                              int M, int N, int K,
                                              short* __restrict__ q_out,
                                              short* __restrict__ k_out,
                                              short* __restrict__ vt_out,
                                              float* __restrict__ c_out) {
  __shared__ short As[2][4096];
  __shared__ short Bs[2][4096];
  const int tid  = threadIdx.x;
  const int lane = tid & 63;
  const int wave = tid >> 6;
  const int wm = (wave >> 1) * 64, wn = (wave & 1) * 64;
  const int bm = blockIdx.y * 128, bn = blockIdx.x * 128;
  const int sr = tid >> 2, sc = (tid & 3) * 8;
  const short* Ag = A + (long)(bm + sr) * K + sc;
  const short* Bg = Bt + (long)(bn + sr) * K + sc;
  const int fr = lane & 15, fg = lane >> 4;

  f32x4 acc[4][4];
#pragma unroll
  for (int i = 0; i < 4; ++i)
#pragma unroll
    for (int j = 0; j < 4; ++j) acc[i][j] = (f32x4){0.f, 0.f, 0.f, 0.f};

  auto stage = [&](int buf, int kt) {
    gload16(Ag + kt, &As[buf][tid * 8]);
    gload16(Ag + kt + 64 * K, &As[buf][2048 + tid * 8]);
    gload16(Bg + kt, &Bs[buf][tid * 8]);
    gload16(Bg + kt + 64 * K, &Bs[buf][2048 + tid * 8]);
  };

  stage(0, 0);
  const int NT = K >> 5;
  for (int t = 0; t < NT; ++t) {
    const int cur = t & 1;
    __syncthreads();                 // drains stage issued last iter -> buf[cur] ready
    if (t + 1 < NT) stage(cur ^ 1, (t + 1) << 5);
    bf16x8 af[4], bfr[4];
    const short* Ar = &As[cur][(wm + fr) * 32 + fg * 8];
    const short* Br = &Bs[cur][(wn + fr) * 32 + fg * 8];
#pragma unroll
    for (int mi = 0; mi < 4; ++mi) af[mi] = *(const bf16x8*)(Ar + mi * 16 * 32);
#pragma unroll
    for (int ni = 0; ni < 4; ++ni) bfr[ni] = *(const bf16x8*)(Br + ni * 16 * 32);
#pragma unroll
    for (int mi = 0; mi < 4; ++mi)
#pragma unroll
      for (int ni = 0; ni < 4; ++ni)
        acc[mi][ni] = MFMA(af[mi], bfr[ni], acc[mi][ni]);
  }

#pragma unroll
  for (int mi = 0; mi < 4; ++mi) {
#pragma unroll
    for (int ni = 0; ni < 4; ++ni) {
      const int gcol  = bn + wn + ni * 16 + fr;
      const float bv  = bias[gcol];
      const int grow0 = bm + wm + mi * 16 + fg * 4;
      if (EPI == 0) {
        const int which = gcol >> 10;       // uniform per block (BN=128 within 1024)
        const int e = gcol & 1023;
        const int h = e >> 6, d = e & 63;
#pragma unroll
        for (int r = 0; r < 4; ++r) {
          const int mrow = grow0 + r;
          const int b = mrow >> 11, s = mrow & 2047;
          const short val = f2bf(acc[mi][ni][r] + bv);
          if (which == 0)      q_out[((long)(b * 16 + h) * 2048 + s) * 64 + d] = val;
          else if (which == 1) k_out[((long)(b * 16 + h) * 2048 + s) * 64 + d] = val;
          else                 vt_out[((long)(b * 16 + h) * 64 + d) * 2048 + s] = val;
        }
      } else {
#pragma unroll
        for (int r = 0; r < 4; ++r)
          c_out[(long)(grow0 + r) * N + gcol] = acc[mi][ni][r] + bv;
      }
    }
  }
}

// ---------------- causal flash attention ----------------
// grid (bh=32, 32 strips of 64 q-rows), 256-thread blocks (4 waves x 16 rows).
// K/V tiles (64 keys) staged into XOR-swizzled LDS, double-buffered async
// global_load_lds (stage issued after the barrier, drained at the next one).
// Swapped QK^T (mfma(K,Q)) puts P in the 16x16x16 B-operand layout -> PV from
// registers. Softmax: max/exp on UNSCALED z (scale folded via tmax*SC and
// exp2(fma(z,SC,-m))), native bf16 casts -> v_cvt_pk fusion.

__global__ __launch_bounds__(256, 4) void k_attn(const short* __restrict__ Qb,
                                                 const short* __restrict__ Kb,
                                                 const short* __restrict__ Vt,
                                                 short* __restrict__ Y) {
  __shared__ short smem[2][2][4096];   // [buf][0=K,1=V][64 rows][64 shorts]
  const int bh = blockIdx.x;
  const int strip = 31 - blockIdx.y;   // heavy-first dispatch
  const int qw0 = strip * 64;
  const int b = bh >> 4, h = bh & 15;
  const int tid = threadIdx.x;
  const int w = tid >> 6, lane = tid & 63;
  const int ql = lane & 15, g = lane >> 4;
  const short* Kp = Kb + (long)bh * 2048 * 64;
  const short* Vp = Vt + (long)bh * 64 * 2048;
  const short* Qp = Qb + ((long)bh * 2048 + qw0 + w * 16) * 64;

  const bf16x8 qf0 = *(const bf16x8*)(Qp + ql * 64 + g * 8);
  const bf16x8 qf1 = *(const bf16x8*)(Qp + ql * 64 + 32 + g * 8);

  // staging geometry: thread i covers row r=j*32+(i>>3), chunk slot i&7;
  // source chunk c = (i&7) ^ (r&7)  (inverse-swizzled source, linear dest)
  const int sr_ = tid >> 3, sj_ = tid & 7;

  f32x4 o[4];
#pragma unroll
  for (int df = 0; df < 4; ++df) o[df] = (f32x4){0.f, 0.f, 0.f, 0.f};
  float m = -1e30f, l = 0.f;
  const int nt = strip + 1;
  const float SC = 0.125f * 1.44269504088896341f;  // (1/sqrt(64)) * log2(e)

  {  // prologue stage of tile 0
#pragma unroll
    for (int j = 0; j < 2; ++j) {
      const int r = j * 32 + sr_;
      const int c = sj_ ^ (r & 7);
      gload16(Kp + (long)r * 64 + c * 8, &smem[0][0][j * 2048 + tid * 8]);
      gload16(Vp + (long)r * 2048 + c * 8, &smem[0][1][j * 2048 + tid * 8]);
    }
  }

  for (int t = 0; t < nt; ++t) {
    const int cur = t & 1;
    __syncthreads();                  // waits own vmcnt -> buf[cur] ready, prev reads done
    if (t + 1 < nt) {                 // issue next-tile stage; lands before next barrier
      const int k0n = (t + 1) * 64;
#pragma unroll
      for (int j = 0; j < 2; ++j) {
        const int r = j * 32 + sr_;
        const int c = sj_ ^ (r & 7);
        gload16(Kp + (long)(k0n + r) * 64 + c * 8, &smem[cur ^ 1][0][j * 2048 + tid * 8]);
        gload16(Vp + (long)r * 2048 + k0n + c * 8, &smem[cur ^ 1][1][j * 2048 + tid * 8]);
      }
    }
    const short* Kl = &smem[cur][0][0];
    const short* Vl = &smem[cur][1][0];
    const int kfcap = (t == strip) ? (w + 1) : 4;   // wave-uniform

    // ---- QK^T from LDS (swizzled b128 reads); unscaled masked scores zc ----
    float zc[16];
#pragma unroll
    for (int j = 0; j < 16; ++j) zc[j] = -3.0e38f;
#pragma unroll
    for (int kf = 0; kf < 4; ++kf) {
      if (kf < kfcap) {
        const int r = kf * 16 + ql;
        const bf16x8 ka = *(const bf16x8*)(Kl + r * 64 + ((g ^ (r & 7)) * 8));
        const bf16x8 kb = *(const bf16x8*)(Kl + r * 64 + (((4 + g) ^ (r & 7)) * 8));
        f32x4 zz = (f32x4){0.f, 0.f, 0.f, 0.f};
        zz = MFMA(ka, qf0, zz);       // S^T[k][q], d 0..31
        zz = MFMA(kb, qf1, zz);       // += d 32..63
        if (t < strip || kf < w) {
#pragma unroll
          for (int r4 = 0; r4 < 4; ++r4) zc[kf * 4 + r4] = zz[r4];
        } else {                      // kf == w: diagonal 16x16 block
#pragma unroll
          for (int r4 = 0; r4 < 4; ++r4)
            zc[kf * 4 + r4] = (g * 4 + r4 <= ql) ? zz[r4] : -3.0e38f;
        }
      }
    }
    // ---- tree max on unscaled z + 2 shfl, then scale once ----
    float mx[8];
#pragma unroll
    for (int j = 0; j < 8; ++j) mx[j] = fmaxf(zc[j], zc[j + 8]);
#pragma unroll
    for (int j = 0; j < 4; ++j) mx[j] = fmaxf(mx[j], mx[j + 4]);
    float tz = fmaxf(fmaxf(mx[0], mx[2]), fmaxf(mx[1], mx[3]));
    tz = fmaxf(tz, __shfl_xor(tz, 16));
    tz = fmaxf(tz, __shfl_xor(tz, 32));
    const float tmax = tz * SC;
    // ---- defer-max rescale (T13, log2 domain THR=8) ----
    if (!__all(tmax <= m + 8.0f)) {
      const float nm = fmaxf(m, tmax);
      const float fac = exp2f(m - nm);
      l *= fac;
#pragma unroll
      for (int df = 0; df < 4; ++df) o[df] *= fac;
      m = nm;
    }
    // ---- exp via fused fma(z,SC,-m) + tree sum ----
    float p[16];
#pragma unroll
    for (int j = 0; j < 16; ++j) p[j] = exp2f(fmaf(zc[j], SC, -m));
    float sm[8];
#pragma unroll
    for (int j = 0; j < 8; ++j) sm[j] = p[j] + p[j + 8];
#pragma unroll
    for (int j = 0; j < 4; ++j) sm[j] += sm[j + 4];
    float ts = (sm[0] + sm[1]) + (sm[2] + sm[3]);
    ts += __shfl_xor(ts, 16);
    ts += __shfl_xor(ts, 32);
    l += ts;
    // ---- PV from registers + swizzled V b64 reads ----
#pragma unroll
    for (int kf = 0; kf < 4; ++kf) {
      if (kf < kfcap) {
        s16x4 pk;
        pk[0] = f2bf(p[kf * 4 + 0]);
        pk[1] = f2bf(p[kf * 4 + 1]);
        pk[2] = f2bf(p[kf * 4 + 2]);
        pk[3] = f2bf(p[kf * 4 + 3]);
#pragma unroll
        for (int df = 0; df < 4; ++df) {
          const int d = df * 16 + ql;
          const int c = kf * 2 + (g >> 1);
          const s16x4 vk = *(const s16x4*)(Vl + d * 64 + ((c ^ (d & 7)) * 8) + (g & 1) * 4);
          o[df] = MFMA16(vk, pk, o[df]);   // O^T[d][q]
        }
      }
    }
  }

  // ---- epilogue: divide, transpose via LDS overlay, coalesced store ----
  __syncthreads();                    // all waves done reading K/V buffers
  float* ot = (float*)&smem[0][0][0] + w * 1040;   // per-wave 16x65 floats
  const float linv = 1.f / l;
#pragma unroll
  for (int df = 0; df < 4; ++df)
#pragma unroll
    for (int r = 0; r < 4; ++r)
      ot[ql * 65 + df * 16 + g * 4 + r] = o[df][r] * linv;
  const int q2 = lane >> 2, c4 = (lane & 3) * 16;
  short* Yp = Y + ((long)(b * 2048 + qw0 + w * 16 + q2)) * 1024 + h * 64 + c4;
  s16x8 y0, y1;
#pragma unroll
  for (int j = 0; j < 8; ++j) {
    y0[j] = f2bf(ot[q2 * 65 + c4 + j]);
    y1[j] = f2bf(ot[q2 * 65 + c4 + 8 + j]);
  }
  *(s16x8*)Yp = y0;
  *((s16x8*)(Yp + 8)) = y1;
}

// ---------------- launch ----------------

extern "C" void kernel_launch(void* const* d_in, const int* in_sizes, int n_in,
                              void* d_out, int out_size, void* d_ws, size_t ws_size,
                              hipStream_t stream) {
  const float* x      = (const float*)d_in[0];
  const float* W_attn = (const float*)d_in[1];
  const float* b_attn = (const float*)d_in[2];
  const float* W_proj = (const float*)d_in[3];
  const float* b_proj = (const float*)d_in[4];
  float* out = (float*)d_out;

  char* ws = (char*)d_ws;
  short* x_bf = (short*)(ws);                    //  8 MB  [4096][1024]
  short* Wt_a = (short*)(ws + 8388608);          //  6 MB  [3072][1024]
  short* Wt_p = (short*)(ws + 14680064);         //  2 MB  [1024][1024]
  short* Qb   = (short*)(ws + 16777216);         //  8 MB  [2,16,2048,64]
  short* Kb   = (short*)(ws + 25165824);         //  8 MB  [2,16,2048,64]
  short* Vtb  = (short*)(ws + 33554432);         //  8 MB  [2,16,64,2048]
  short* y_bf = (short*)(ws + 41943040);         //  8 MB  [4096][1024]

  k_f32_to_bf16<<<4096, 256, 0, stream>>>(x, x_bf, 4194304);
  k_transpose_bf<<<dim3(96, 32), 256, 0, stream>>>(W_attn, Wt_a, 1024, 3072);
  k_transpose_bf<<<dim3(32, 32), 256, 0, stream>>>(W_proj, Wt_p, 1024, 1024);
  k_gemm<0><<<dim3(24, 32), 256, 0, stream>>>(x_bf, Wt_a, b_attn, 4096, 3072, 1024,
                                              Qb, Kb, Vtb, nullptr);
  k_attn<<<dim3(32, 32), 256, 0, stream>>>(Qb, Kb, Vtb, y_bf);
  k_gemm<1><<<dim3(8, 32), 256, 0, stream>>>(y_bf, Wt_p, b_proj, 4096, 1024, 1024,
                                             nullptr, nullptr, nullptr, out);
}

// Round 7
// 127.739 us; speedup vs baseline: 2.4033x; 1.0104x over previous
//
#include <hip/hip_runtime.h>
#include <hip/hip_bf16.h>
#include <stdint.h>

// CausalSelfAttention: x[2,2048,1024] -> qkv -> 16-head causal attn -> proj.
// bf16 MFMA pipeline, fp32 accumulation everywhere.

typedef __attribute__((ext_vector_type(4))) float  f32x4;
typedef __attribute__((ext_vector_type(8))) __bf16 bf16x8;
typedef __attribute__((ext_vector_type(4))) short  s16x4;
typedef __attribute__((ext_vector_type(8))) short  s16x8;

#define MFMA(a, b, c) __builtin_amdgcn_mfma_f32_16x16x32_bf16((a), (b), (c), 0, 0, 0)

// 16x16x16 bf16 MFMA: device pass has it on gfx950; host pass only parses.
#if defined(__HIP_DEVICE_COMPILE__)
#define MFMA16(a, b, c) __builtin_amdgcn_mfma_f32_16x16x16bf16_1k((a), (b), (c), 0, 0, 0)
#else
#define MFMA16(a, b, c) (c)
#endif

// f32 -> bf16 RTNE. Device: native cast so the compiler can fuse pairs into
// v_cvt_pk_bf16_f32. Host: parse-only bit-twiddle equivalent.
__device__ __forceinline__ short f2bf(float x) {
#if defined(__HIP_DEVICE_COMPILE__)
  union { __bf16 b; short s; } u; u.b = (__bf16)x; return u.s;
#else
  union { float f; unsigned u; } v; v.f = x;
  unsigned r = v.u + 0x7FFFu + ((v.u >> 16) & 1u);
  return (short)(r >> 16);
#endif
}

__device__ __forceinline__ void gload16(const void* gptr, void* lptr) {
  __builtin_amdgcn_global_load_lds(
      (const __attribute__((address_space(1))) void*)gptr,
      (__attribute__((address_space(3))) void*)lptr, 16, 0, 0);
}

// ---------------- conversion kernels ----------------

__global__ __launch_bounds__(256) void k_f32_to_bf16(const float* __restrict__ in,
                                                     short* __restrict__ out, int n) {
  int i = (blockIdx.x * 256 + threadIdx.x) * 4;
  if (i >= n) return;
  float4 v = *(const float4*)(in + i);
  s16x4 o;
  o[0] = f2bf(v.x); o[1] = f2bf(v.y); o[2] = f2bf(v.z); o[3] = f2bf(v.w);
  *(s16x4*)(out + i) = o;
}

// W [R][C] fp32 row-major  ->  Wt [C][R] bf16 (i.e. [n][k] layout for GEMM B^T)
__global__ __launch_bounds__(256) void k_transpose_bf(const float* __restrict__ W,
                                                      short* __restrict__ Wt, int R, int C) {
  __shared__ float tile[32][33];
  const int tx = threadIdx.x & 31, ty = threadIdx.x >> 5;  // ty 0..7
  const int bx = blockIdx.x * 32, by = blockIdx.y * 32;
#pragma unroll
  for (int i = 0; i < 4; ++i)
    tile[ty + i * 8][tx] = W[(long)(by + ty + i * 8) * C + bx + tx];
  __syncthreads();
#pragma unroll
  for (int i = 0; i < 4; ++i)
    Wt[(long)(bx + ty + i * 8) * R + by + tx] = f2bf(tile[tx][ty + i * 8]);
}

// ---------------- GEMM: C[M][N] = A[M][K] * Bt[N][K]^T + bias ----------------
// 128x128 tile, BK=32, 4 waves (2x2 of 64x64). TRIPLE-buffered LDS with
// counted vmcnt (T4): per iter wait only for tile t's 4 loads
// (s_waitcnt vmcnt(4)) + raw s_barrier -> tiles t+1,t+2 stay in flight
// across the barrier. 48 KB LDS = 3 blocks/CU = exactly the grid cap.
// EPI==0: scatter to Q[b,h,s,d] (pre-scaled), K[b,h,s,d], Vt[b,h,d,s] (bf16)
// EPI==1: fp32 row-major output

template <int EPI>
__global__ __launch_bounds__(256) void k_gemm(const short* __restrict__ A,
                                              const short* __restrict__ Bt,
                                              const float* __restrict__ bias,
                                              int M, int N, int K,
                                              short* __restrict__ q_out,
                                              short* __restrict__ k_out,
                                              short* __restrict__ vt_out,
                                              float* __restrict__ c_out) {
  __shared__ short As[3][4096];
  __shared__ short Bs[3][4096];
  const int tid  = threadIdx.x;
  const int lane = tid & 63;
  const int wave = tid >> 6;
  const int wm = (wave >> 1) * 64, wn = (wave & 1) * 64;
  const int bm = blockIdx.y * 128, bn = blockIdx.x * 128;
  const int sr = tid >> 2, sc = (tid & 3) * 8;
  const short* Ag = A + (long)(bm + sr) * K + sc;
  const short* Bg = Bt + (long)(bn + sr) * K + sc;
  const int fr = lane & 15, fg = lane >> 4;

  f32x4 acc[4][4];
#pragma unroll
  for (int i = 0; i < 4; ++i)
#pragma unroll
    for (int j = 0; j < 4; ++j) acc[i][j] = (f32x4){0.f, 0.f, 0.f, 0.f};

  auto stage = [&](int buf, int kt) {
    gload16(Ag + kt, &As[buf][tid * 8]);
    gload16(Ag + kt + 64 * K, &As[buf][2048 + tid * 8]);
    gload16(Bg + kt, &Bs[buf][tid * 8]);
    gload16(Bg + kt + 64 * K, &Bs[buf][2048 + tid * 8]);
  };
  auto compute = [&](int buf) {
    bf16x8 af[4], bfr[4];
    const short* Ar = &As[buf][(wm + fr) * 32 + fg * 8];
    const short* Br = &Bs[buf][(wn + fr) * 32 + fg * 8];
#pragma unroll
    for (int mi = 0; mi < 4; ++mi) af[mi] = *(const bf16x8*)(Ar + mi * 16 * 32);
#pragma unroll
    for (int ni = 0; ni < 4; ++ni) bfr[ni] = *(const bf16x8*)(Br + ni * 16 * 32);
#pragma unroll
    for (int mi = 0; mi < 4; ++mi)
#pragma unroll
      for (int ni = 0; ni < 4; ++ni)
        acc[mi][ni] = MFMA(af[mi], bfr[ni], acc[mi][ni]);
  };

  const int NT = K >> 5;
  stage(0, 0);
  stage(1, 32);
  for (int t = 0; t < NT - 1; ++t) {
    // wait only for tile t's 4 loads (4 newer stay in flight), then barrier
    asm volatile("s_waitcnt vmcnt(4)" ::: "memory");
    __builtin_amdgcn_s_barrier();
    asm volatile("" ::: "memory");
    if (t + 2 < NT) stage((t + 2) % 3, (t + 2) << 5);
    compute(t % 3);
  }
  asm volatile("s_waitcnt vmcnt(0)" ::: "memory");
  __builtin_amdgcn_s_barrier();
  asm volatile("" ::: "memory");
  compute((NT - 1) % 3);

  const float QSC = 0.125f * 1.44269504088896341f;  // fold attn scale into Q
#pragma unroll
  for (int mi = 0; mi < 4; ++mi) {
#pragma unroll
    for (int ni = 0; ni < 4; ++ni) {
      const int gcol  = bn + wn + ni * 16 + fr;
      const float bv  = bias[gcol];
      const int grow0 = bm + wm + mi * 16 + fg * 4;
      if (EPI == 0) {
        const int which = gcol >> 10;       // uniform per block (BN=128 within 1024)
        const int e = gcol & 1023;
        const int h = e >> 6, d = e & 63;
#pragma unroll
        for (int r = 0; r < 4; ++r) {
          const int mrow = grow0 + r;
          const int b = mrow >> 11, s = mrow & 2047;
          const float av = acc[mi][ni][r] + bv;
          if (which == 0)      q_out[((long)(b * 16 + h) * 2048 + s) * 64 + d] = f2bf(av * QSC);
          else if (which == 1) k_out[((long)(b * 16 + h) * 2048 + s) * 64 + d] = f2bf(av);
          else                 vt_out[((long)(b * 16 + h) * 64 + d) * 2048 + s] = f2bf(av);
        }
      } else {
#pragma unroll
        for (int r = 0; r < 4; ++r)
          c_out[(long)(grow0 + r) * N + gcol] = acc[mi][ni][r] + bv;
      }
    }
  }
}

// ---------------- causal flash attention ----------------
// grid (bh=32, 32 strips of 64 q-rows), 256-thread blocks (4 waves x 16 rows).
// K/V tiles (64 keys) in XOR-swizzled LDS, double-buffered global_load_lds.
// Swapped QK^T (mfma(K,Q)) puts P in the 16x16x16 B-operand layout -> PV from
// registers. Q pre-scaled by 0.125*log2e in the QKV epilogue, so scores are
// already in exp2 domain. l-sum computed on the MFMA pipe via a ones-fragment
// (removes the VALU sum tree + 2 shfl; every lane ends with its own l).
// Max via nested fmaxf (v_max3). setprio(1) around MFMA clusters (T5).

__global__ __launch_bounds__(256, 4) void k_attn(const short* __restrict__ Qb,
                                                 const short* __restrict__ Kb,
                                                 const short* __restrict__ Vt,
                                                 short* __restrict__ Y) {
  __shared__ short smem[2][2][4096];   // [buf][0=K,1=V][64 rows][64 shorts]
  const int bh = blockIdx.x;
  const int strip = 31 - blockIdx.y;   // heavy-first dispatch
  const int qw0 = strip * 64;
  const int b = bh >> 4, h = bh & 15;
  const int tid = threadIdx.x;
  const int w = tid >> 6, lane = tid & 63;
  const int ql = lane & 15, g = lane >> 4;
  const short* Kp = Kb + (long)bh * 2048 * 64;
  const short* Vp = Vt + (long)bh * 64 * 2048;
  const short* Qp = Qb + ((long)bh * 2048 + qw0 + w * 16) * 64;

  const bf16x8 qf0 = *(const bf16x8*)(Qp + ql * 64 + g * 8);
  const bf16x8 qf1 = *(const bf16x8*)(Qp + ql * 64 + 32 + g * 8);

  // staging geometry: thread i covers row r=j*32+(i>>3), chunk slot i&7;
  // source chunk c = (i&7) ^ (r&7)  (inverse-swizzled source, linear dest)
  const int sr_ = tid >> 3, sj_ = tid & 7;

  s16x4 ones;
  ones[0] = ones[1] = ones[2] = ones[3] = (short)0x3F80;  // bf16 1.0

  f32x4 o[4];
#pragma unroll
  for (int df = 0; df < 4; ++df) o[df] = (f32x4){0.f, 0.f, 0.f, 0.f};
  f32x4 o_l = (f32x4){0.f, 0.f, 0.f, 0.f};   // row-sum accumulator (l)
  float m = -1e30f;
  const int nt = strip + 1;

  {  // prologue stage of tile 0
#pragma unroll
    for (int j = 0; j < 2; ++j) {
      const int r = j * 32 + sr_;
      const int c = sj_ ^ (r & 7);
      gload16(Kp + (long)r * 64 + c * 8, &smem[0][0][j * 2048 + tid * 8]);
      gload16(Vp + (long)r * 2048 + c * 8, &smem[0][1][j * 2048 + tid * 8]);
    }
  }

  for (int t = 0; t < nt; ++t) {
    const int cur = t & 1;
    __syncthreads();                  // waits own vmcnt -> buf[cur] ready, prev reads done
    if (t + 1 < nt) {                 // issue next-tile stage; lands before next barrier
      const int k0n = (t + 1) * 64;
#pragma unroll
      for (int j = 0; j < 2; ++j) {
        const int r = j * 32 + sr_;
        const int c = sj_ ^ (r & 7);
        gload16(Kp + (long)(k0n + r) * 64 + c * 8, &smem[cur ^ 1][0][j * 2048 + tid * 8]);
        gload16(Vp + (long)r * 2048 + k0n + c * 8, &smem[cur ^ 1][1][j * 2048 + tid * 8]);
      }
    }
    const short* Kl = &smem[cur][0][0];
    const short* Vl = &smem[cur][1][0];
    const bool diag = (t == strip);

    // ---- QK^T from LDS (swizzled b128 reads); scores already exp2-scaled ----
    float z[16];
    __builtin_amdgcn_s_setprio(1);
#pragma unroll
    for (int kf = 0; kf < 4; ++kf) {
      if (!diag || kf <= w) {
        const int r = kf * 16 + ql;
        const bf16x8 ka = *(const bf16x8*)(Kl + r * 64 + ((g ^ (r & 7)) * 8));
        const bf16x8 kb = *(const bf16x8*)(Kl + r * 64 + (((4 + g) ^ (r & 7)) * 8));
        f32x4 zz = (f32x4){0.f, 0.f, 0.f, 0.f};
        zz = MFMA(ka, qf0, zz);       // S^T[k][q], d 0..31
        zz = MFMA(kb, qf1, zz);       // += d 32..63
        if (diag && kf == w) {        // diagonal 16x16 block: per-element mask
#pragma unroll
          for (int r4 = 0; r4 < 4; ++r4)
            z[kf * 4 + r4] = (g * 4 + r4 <= ql) ? zz[r4] : -3.0e38f;
        } else {
#pragma unroll
          for (int r4 = 0; r4 < 4; ++r4) z[kf * 4 + r4] = zz[r4];
        }
      } else {
#pragma unroll
        for (int r4 = 0; r4 < 4; ++r4) z[kf * 4 + r4] = -3.0e38f;
      }
    }
    __builtin_amdgcn_s_setprio(0);

    // ---- max: nested fmaxf -> v_max3 tree, + 2 shfl ----
    const float t1 = fmaxf(fmaxf(z[0], z[1]), z[2]);
    const float t2 = fmaxf(fmaxf(z[3], z[4]), z[5]);
    const float t3 = fmaxf(fmaxf(z[6], z[7]), z[8]);
    const float t4 = fmaxf(fmaxf(z[9], z[10]), z[11]);
    const float t5 = fmaxf(fmaxf(z[12], z[13]), z[14]);
    float tz = fmaxf(fmaxf(fmaxf(t1, t2), t3), fmaxf(fmaxf(t4, t5), z[15]));
    tz = fmaxf(tz, __shfl_xor(tz, 16));
    tz = fmaxf(tz, __shfl_xor(tz, 32));
    // ---- defer-max rescale (T13, log2 domain THR=8) ----
    if (!__all(tz <= m + 8.0f)) {
      const float nm = fmaxf(m, tz);
      const float fac = exp2f(m - nm);
#pragma unroll
      for (int df = 0; df < 4; ++df) o[df] *= fac;
      o_l *= fac;
      m = nm;
    }
    // ---- P = exp2(z - m) straight into bf16 fragments; PV + l via MFMA ----
    __builtin_amdgcn_s_setprio(1);
#pragma unroll
    for (int kf = 0; kf < 4; ++kf) {
      if (!diag || kf <= w) {
        s16x4 pk;
        pk[0] = f2bf(exp2f(z[kf * 4 + 0] - m));
        pk[1] = f2bf(exp2f(z[kf * 4 + 1] - m));
        pk[2] = f2bf(exp2f(z[kf * 4 + 2] - m));
        pk[3] = f2bf(exp2f(z[kf * 4 + 3] - m));
        o_l = MFMA16(ones, pk, o_l);       // row-sum on the matrix pipe
#pragma unroll
        for (int df = 0; df < 4; ++df) {
          const int d = df * 16 + ql;
          const int c = kf * 2 + (g >> 1);
          const s16x4 vk = *(const s16x4*)(Vl + d * 64 + ((c ^ (d & 7)) * 8) + (g & 1) * 4);
          o[df] = MFMA16(vk, pk, o[df]);   // O^T[d][q]
        }
      }
    }
    __builtin_amdgcn_s_setprio(0);
  }

  // ---- epilogue: divide, transpose via LDS overlay, coalesced store ----
  __syncthreads();                    // all waves done reading K/V buffers
  float* ot = (float*)&smem[0][0][0] + w * 1040;   // per-wave 16x65 floats
  const float linv = 1.f / o_l[0];    // every lane holds l for its q=ql
#pragma unroll
  for (int df = 0; df < 4; ++df)
#pragma unroll
    for (int r = 0; r < 4; ++r)
      ot[ql * 65 + df * 16 + g * 4 + r] = o[df][r] * linv;
  const int q2 = lane >> 2, c4 = (lane & 3) * 16;
  short* Yp = Y + ((long)(b * 2048 + qw0 + w * 16 + q2)) * 1024 + h * 64 + c4;
  s16x8 y0, y1;
#pragma unroll
  for (int j = 0; j < 8; ++j) {
    y0[j] = f2bf(ot[q2 * 65 + c4 + j]);
    y1[j] = f2bf(ot[q2 * 65 + c4 + 8 + j]);
  }
  *(s16x8*)Yp = y0;
  *((s16x8*)(Yp + 8)) = y1;
}

// ---------------- launch ----------------

extern "C" void kernel_launch(void* const* d_in, const int* in_sizes, int n_in,
                              void* d_out, int out_size, void* d_ws, size_t ws_size,
                              hipStream_t stream) {
  const float* x      = (const float*)d_in[0];
  const float* W_attn = (const float*)d_in[1];
  const float* b_attn = (const float*)d_in[2];
  const float* W_proj = (const float*)d_in[3];
  const float* b_proj = (const float*)d_in[4];
  float* out = (float*)d_out;

  char* ws = (char*)d_ws;
  short* x_bf = (short*)(ws);                    //  8 MB  [4096][1024]
  short* Wt_a = (short*)(ws + 8388608);          //  6 MB  [3072][1024]
  short* Wt_p = (short*)(ws + 14680064);         //  2 MB  [1024][1024]
  short* Qb   = (short*)(ws + 16777216);         //  8 MB  [2,16,2048,64]
  short* Kb   = (short*)(ws + 25165824);         //  8 MB  [2,16,2048,64]
  short* Vtb  = (short*)(ws + 33554432);         //  8 MB  [2,16,64,2048]
  short* y_bf = (short*)(ws + 41943040);         //  8 MB  [4096][1024]

  k_f32_to_bf16<<<4096, 256, 0, stream>>>(x, x_bf, 4194304);
  k_transpose_bf<<<dim3(96, 32), 256, 0, stream>>>(W_attn, Wt_a, 1024, 3072);
  k_transpose_bf<<<dim3(32, 32), 256, 0, stream>>>(W_proj, Wt_p, 1024, 1024);
  k_gemm<0><<<dim3(24, 32), 256, 0, stream>>>(x_bf, Wt_a, b_attn, 4096, 3072, 1024,
                                              Qb, Kb, Vtb, nullptr);
  k_attn<<<dim3(32, 32), 256, 0, stream>>>(Qb, Kb, Vtb, y_bf);
  k_gemm<1><<<dim3(8, 32), 256, 0, stream>>>(y_bf, Wt_p, b_proj, 4096, 1024, 1024,
                                             nullptr, nullptr, nullptr, out);
}